// Round 2
// baseline (682.261 us; speedup 1.0000x reference)
//
#include <hip/hip_runtime.h>
#include <stdint.h>

#define Bb 8
#define Ss 2048
#define Hh 16
#define Aa 128
#define Dd 128
#define NGATE 384
#define KDIM 256
#define NCH 16
#define CLEN 128
#define ROWS (Bb*Ss)          // 16384 (b,s) rows
#define ROWSTR (Hh*Aa)        // 2048 elements per (b,s) row

typedef float f32x4 __attribute__((ext_vector_type(4)));
typedef __bf16 bf16x8 __attribute__((ext_vector_type(8)));
typedef unsigned short u16x8 __attribute__((ext_vector_type(8)));

static __device__ __forceinline__ unsigned short f2bf(float f){
  unsigned int u = __builtin_bit_cast(unsigned int, f);
  u += 0x7FFFu + ((u >> 16) & 1u);
  return (unsigned short)(u >> 16);
}
static __device__ __forceinline__ float bf2f(unsigned short s){
  unsigned int u = ((unsigned int)s) << 16;
  return __builtin_bit_cast(float, u);
}
static __device__ __forceinline__ float sigf(float x){ return 1.0f/(1.0f + __expf(-x)); }

static __device__ __forceinline__ void gload16(const void* g, void* l){
  __builtin_amdgcn_global_load_lds(
      (const __attribute__((address_space(1))) void*)g,
      (__attribute__((address_space(3))) void*)l, 16, 0, 0);
}

// ---- weight conversion: fp32 -> bf16, [h][kk-tile] XOR-swizzled physical layout ----
// logical (n,kl) in a [N][64] bf16 tile -> byte L = n*128+kl*2 -> physical P = L ^ ((n&7)<<4)
__global__ void k_conv_whid(const float* __restrict__ w, unsigned short* __restrict__ wt){
  int idx = blockIdx.x*256 + threadIdx.x;
  const int total = Hh*KDIM*NGATE;
  for (; idx < total; idx += gridDim.x*256){
    int o = idx % NGATE; int k = (idx/NGATE) % KDIM; int h = idx/(NGATE*KDIM);
    int g = o >> 7, d = o & 127;                     // gate, channel
    int n = (d >> 4)*48 + g*16 + (d & 15);           // interleave (ig,fg,hd) per 16-col block
    int kk = k >> 6, kl = k & 63;
    int L = n*128 + kl*2;
    int P = L ^ ((n & 7) << 4);
    wt[(size_t)h*(NGATE*KDIM) + kk*(NGATE*64) + (P>>1)] = f2bf(w[idx]);
  }
}
__global__ void k_conv_wog(const float* __restrict__ w, unsigned short* __restrict__ wt){
  int idx = blockIdx.x*256 + threadIdx.x;
  const int total = Hh*KDIM*Dd;
  for (; idx < total; idx += gridDim.x*256){
    int o = idx % Dd; int k = (idx/Dd) % KDIM; int h = idx/(Dd*KDIM);
    int kk = k >> 6, kl = k & 63;
    int L = o*128 + kl*2;
    int P = L ^ ((o & 7) << 4);
    wt[(size_t)h*(Dd*KDIM) + kk*(Dd*64) + (P>>1)] = f2bf(w[idx]);
  }
}

// ---- cumsum pass A: chunk totals ----
__global__ void k_cumsum_a(const float* __restrict__ x, float* __restrict__ totals){
  int c = blockIdx.x;                       // ((b*Hh+h)*NCH + k)
  int k = c % NCH; int hb = c / NCH;
  int b = hb / Hh, h = hb % Hh;
  int a = threadIdx.x;
  const float* p = x + ((size_t)(b*Ss + k*CLEN)*Hh + h)*Aa + a;
  float run = 0.f;
  #pragma unroll 4
  for (int i = 0; i < CLEN; ++i) run += p[(size_t)i*ROWSTR];
  totals[(size_t)c*Aa + a] = run;
}

// ---- cumsum pass C: carry-in + write bf16 csum ----
__global__ void k_cumsum_c(const float* __restrict__ x, const float* __restrict__ totals,
                           unsigned short* __restrict__ csum){
  int c = blockIdx.x;
  int k = c % NCH; int hb = c / NCH;
  int b = hb / Hh, h = hb % Hh;
  int a = threadIdx.x;
  const float* tp = totals + (size_t)hb*NCH*Aa + a;
  float run = 0.f;
  for (int j = 0; j < k; ++j) run += tp[(size_t)j*Aa];
  const float* p = x + ((size_t)(b*Ss + k*CLEN)*Hh + h)*Aa + a;
  unsigned short* q = csum + ((size_t)(b*Ss + k*CLEN)*Hh + h)*Aa + a;
  #pragma unroll 2
  for (int i = 0; i < CLEN; ++i){
    run += p[(size_t)i*ROWSTR];
    q[(size_t)i*ROWSTR] = f2bf(run);
  }
}

// ---- LN stats per (b,s) over H*A = 2048 values ----
__global__ void k_stats(const unsigned short* __restrict__ csum, float2* __restrict__ mr){
  int r = blockIdx.x;
  int t = threadIdx.x;                      // 256
  const u16x8 v = *(const u16x8*)(csum + (size_t)r*ROWSTR + t*8);
  float s = 0.f, q = 0.f;
  #pragma unroll
  for (int i = 0; i < 8; ++i){ float f = bf2f(v[i]); s += f; q += f*f; }
  #pragma unroll
  for (int off = 32; off; off >>= 1){ s += __shfl_down(s, off); q += __shfl_down(q, off); }
  __shared__ float ls[4], lq[4];
  int wid = t >> 6, lane = t & 63;
  if (lane == 0){ ls[wid] = s; lq[wid] = q; }
  __syncthreads();
  if (t == 0){
    float S2 = ls[0]+ls[1]+ls[2]+ls[3], Q = lq[0]+lq[1]+lq[2]+lq[3];
    float mu = S2 * (1.0f/(float)ROWSTR);
    float var = Q * (1.0f/(float)ROWSTR) - mu*mu;
    mr[r] = make_float2(mu, rsqrtf(var + 1e-6f));
  }
}

// ---- gates GEMM: [x | LN(csum)] (128x256) @ w_hid_t -> f,u packed bf16x2 ----
__launch_bounds__(512, 4)
__global__ void k_gates(const float* __restrict__ x, const unsigned short* __restrict__ csum,
                        const float2* __restrict__ mr, const float* __restrict__ ln_g,
                        const float* __restrict__ ln_b, const unsigned short* __restrict__ wht,
                        const float* __restrict__ b_hid, unsigned int* __restrict__ fu){
  __shared__ unsigned short lA[128*72];
  __shared__ unsigned short lB[NGATE*64];       // swizzled physical, 49152 B
  const int h = blockIdx.y;
  const int m0 = blockIdx.x * 128;
  const int tid = threadIdx.x;
  const int lane = tid & 63, wid = tid >> 6;
  const int wm = wid >> 1, wn = wid & 1;        // 4x2 wave grid: 32 rows x 192 cols each
  f32x4 acc[2][12];
  #pragma unroll
  for (int i = 0; i < 2; ++i)
    #pragma unroll
    for (int j = 0; j < 12; ++j) acc[i][j] = (f32x4){0.f,0.f,0.f,0.f};

  const int arow = tid >> 2;                    // 0..127
  const int akg  = (tid & 3) * 16;              // 0,16,32,48
  const int r_g  = m0 + arow;
  const char* wsrc = (const char*)(wht + (size_t)h*(NGATE*KDIM));

  for (int kk = 0; kk < 4; ++kk){
    __syncthreads();
    // B: async global->LDS, 6 x 8192 B (wave-uniform base + lane*16)
    {
      const char* gb = wsrc + kk*(NGATE*64*2);
      #pragma unroll
      for (int it = 0; it < 6; ++it){
        int off = it*8192 + tid*16;
        gload16(gb + off, (char*)lB + off);
      }
    }
    { // stage A (128 x 64 bf16), fp32->bf16 (+LN for csum half)
      u16x8 t0, t1;
      if (kk < 2){
        const float4* px = (const float4*)(x + (size_t)r_g*ROWSTR + h*Aa + kk*64 + akg);
        float4 v0 = px[0], v1 = px[1], v2 = px[2], v3 = px[3];
        t0[0]=f2bf(v0.x); t0[1]=f2bf(v0.y); t0[2]=f2bf(v0.z); t0[3]=f2bf(v0.w);
        t0[4]=f2bf(v1.x); t0[5]=f2bf(v1.y); t0[6]=f2bf(v1.z); t0[7]=f2bf(v1.w);
        t1[0]=f2bf(v2.x); t1[1]=f2bf(v2.y); t1[2]=f2bf(v2.z); t1[3]=f2bf(v2.w);
        t1[4]=f2bf(v3.x); t1[5]=f2bf(v3.y); t1[6]=f2bf(v3.z); t1[7]=f2bf(v3.w);
      } else {
        int a0 = (kk-2)*64 + akg;
        const u16x8* pc = (const u16x8*)(csum + (size_t)r_g*ROWSTR + h*Aa + a0);
        u16x8 c0 = pc[0], c1 = pc[1];
        float2 m = mr[r_g];
        const float* pg = ln_g + h*Aa + a0;
        const float* pb = ln_b + h*Aa + a0;
        #pragma unroll
        for (int i = 0; i < 8; ++i){
          t0[i] = f2bf((bf2f(c0[i]) - m.x)*m.y*pg[i]   + pb[i]);
          t1[i] = f2bf((bf2f(c1[i]) - m.x)*m.y*pg[8+i] + pb[8+i]);
        }
      }
      u16x8* dst = (u16x8*)&lA[arow*72 + akg];
      dst[0] = t0; dst[1] = t1;
    }
    __syncthreads();
    #pragma unroll
    for (int ks = 0; ks < 2; ++ks){
      int kb = ks*32 + (lane >> 4)*8;           // element index within 64-col tile
      bf16x8 a0 = __builtin_bit_cast(bf16x8, *(const u16x8*)&lA[(wm*32 +      (lane&15))*72 + kb]);
      bf16x8 a1 = __builtin_bit_cast(bf16x8, *(const u16x8*)&lA[(wm*32 + 16 + (lane&15))*72 + kb]);
      #pragma unroll
      for (int j = 0; j < 12; ++j){
        int n = wn*192 + j*16 + (lane&15);
        int bbyte = (n*128 + kb*2) ^ ((n & 7) << 4);
        bf16x8 bv = __builtin_bit_cast(bf16x8, *(const u16x8*)((const char*)lB + bbyte));
        acc[0][j] = __builtin_amdgcn_mfma_f32_16x16x32_bf16(a0, bv, acc[0][j], 0, 0, 0);
        acc[1][j] = __builtin_amdgcn_mfma_f32_16x16x32_bf16(a1, bv, acc[1][j], 0, 0, 0);
      }
    }
  }
  // epilogue: sigmoid/relu pointwise, pack (u,f) as 2xbf16
  const int ln15 = lane & 15, lq = lane >> 4;
  #pragma unroll
  for (int mf = 0; mf < 2; ++mf){
    int rowb = m0 + wm*32 + mf*16 + lq*4;
    #pragma unroll
    for (int tb = 0; tb < 4; ++tb){
      int d = (wn*4 + tb)*16 + ln15;
      float big = b_hid[h*NGATE + d];
      float bfg = b_hid[h*NGATE + 128 + d];
      float bhd = b_hid[h*NGATE + 256 + d];
      f32x4 aig = acc[mf][tb*3+0];
      f32x4 afg = acc[mf][tb*3+1];
      f32x4 ahd = acc[mf][tb*3+2];
      #pragma unroll
      for (int r = 0; r < 4; ++r){
        float fg = sigf(afg[r] + bfg);
        float uu = sigf(aig[r] + big) * fmaxf(ahd[r] + bhd, 0.0f);
        fu[(size_t)(rowb + r)*ROWSTR + h*Dd + d] =
          ((unsigned int)f2bf(uu) << 16) | (unsigned int)f2bf(fg);
      }
    }
  }
}

// ---- recurrence pass A: per-chunk (F, C) summaries ----
__global__ void k_recur_a(const unsigned int* __restrict__ fu,
                          float* __restrict__ Fc, float* __restrict__ Cc){
  int c = blockIdx.x;
  int k = c % NCH; int hb = c / NCH;
  int b = hb / Hh, h = hb % Hh;
  int d = threadIdx.x;
  const unsigned int* p = fu + ((size_t)(b*Ss + k*CLEN)*Hh + h)*Dd + d;
  float F = 1.f, C = 0.f;
  #pragma unroll 4
  for (int i = 0; i < CLEN; ++i){
    unsigned int v = p[(size_t)i*ROWSTR];
    float f = bf2f((unsigned short)v);
    float u = bf2f((unsigned short)(v >> 16));
    C = fmaf(f, C, u);
    F *= f;
  }
  Fc[(size_t)c*Dd + d] = F;
  Cc[(size_t)c*Dd + d] = C;
}

// ---- recurrence pass C: carry-in + write cell (fp32) into d_out ----
__global__ void k_recur_c(const unsigned int* __restrict__ fu, const float* __restrict__ Fc,
                          const float* __restrict__ Cc, const float* __restrict__ init_cx,
                          float* __restrict__ out){
  int c = blockIdx.x;
  int k = c % NCH; int hb = c / NCH;
  int b = hb / Hh, h = hb % Hh;
  int d = threadIdx.x;
  float carry = init_cx[h*Dd + d];
  const float* fp = Fc + (size_t)hb*NCH*Dd + d;
  const float* cp = Cc + (size_t)hb*NCH*Dd + d;
  for (int j = 0; j < k; ++j) carry = fmaf(fp[(size_t)j*Dd], carry, cp[(size_t)j*Dd]);
  const unsigned int* p = fu + ((size_t)(b*Ss + k*CLEN)*Hh + h)*Dd + d;
  float* q = out + ((size_t)(b*Ss + k*CLEN)*Hh + h)*Dd + d;
  #pragma unroll 2
  for (int i = 0; i < CLEN; ++i){
    unsigned int v = p[(size_t)i*ROWSTR];
    float f = bf2f((unsigned short)v);
    float u = bf2f((unsigned short)(v >> 16));
    carry = fmaf(f, carry, u);
    q[(size_t)i*ROWSTR] = carry;
  }
}

// ---- og GEMM: [x | cell] @ w_og_t -> sigmoid -> out = og*cell (in-place over cell) ----
__launch_bounds__(512, 4)
__global__ void k_og(const float* __restrict__ x, const unsigned short* __restrict__ wot,
                     const float* __restrict__ b_og, float* __restrict__ out){
  __shared__ unsigned short lA[128*72];
  __shared__ unsigned short lB[Dd*64];          // swizzled physical, 16384 B
  const int h = blockIdx.y;
  const int m0 = blockIdx.x * 128;
  const int tid = threadIdx.x;
  const int lane = tid & 63, wid = tid >> 6;
  const int wm = wid >> 1, wn = wid & 1;        // 4x2: 32 rows x 64 cols per wave
  f32x4 acc[2][4];
  #pragma unroll
  for (int i = 0; i < 2; ++i)
    #pragma unroll
    for (int j = 0; j < 4; ++j) acc[i][j] = (f32x4){0.f,0.f,0.f,0.f};

  const int arow = tid >> 2;
  const int akg  = (tid & 3) * 16;
  const int r_g  = m0 + arow;
  const char* wsrc = (const char*)(wot + (size_t)h*(Dd*KDIM));

  for (int kk = 0; kk < 4; ++kk){
    __syncthreads();
    {
      const char* gb = wsrc + kk*(Dd*64*2);
      #pragma unroll
      for (int it = 0; it < 2; ++it){
        int off = it*8192 + tid*16;
        gload16(gb + off, (char*)lB + off);
      }
    }
    { // stage A: k<128 from x, k>=128 from cell (resident in out)
      const float* src = (kk < 2)
        ? (x   + (size_t)r_g*ROWSTR + h*Aa + kk*64 + akg)
        : (out + (size_t)r_g*ROWSTR + h*Dd + (kk-2)*64 + akg);
      const float4* p4 = (const float4*)src;
      float4 v0 = p4[0], v1 = p4[1], v2 = p4[2], v3 = p4[3];
      u16x8 t0, t1;
      t0[0]=f2bf(v0.x); t0[1]=f2bf(v0.y); t0[2]=f2bf(v0.z); t0[3]=f2bf(v0.w);
      t0[4]=f2bf(v1.x); t0[5]=f2bf(v1.y); t0[6]=f2bf(v1.z); t0[7]=f2bf(v1.w);
      t1[0]=f2bf(v2.x); t1[1]=f2bf(v2.y); t1[2]=f2bf(v2.z); t1[3]=f2bf(v2.w);
      t1[4]=f2bf(v3.x); t1[5]=f2bf(v3.y); t1[6]=f2bf(v3.z); t1[7]=f2bf(v3.w);
      u16x8* dst = (u16x8*)&lA[arow*72 + akg];
      dst[0] = t0; dst[1] = t1;
    }
    __syncthreads();
    #pragma unroll
    for (int ks = 0; ks < 2; ++ks){
      int kb = ks*32 + (lane >> 4)*8;
      bf16x8 a0 = __builtin_bit_cast(bf16x8, *(const u16x8*)&lA[(wm*32 +      (lane&15))*72 + kb]);
      bf16x8 a1 = __builtin_bit_cast(bf16x8, *(const u16x8*)&lA[(wm*32 + 16 + (lane&15))*72 + kb]);
      #pragma unroll
      for (int j = 0; j < 4; ++j){
        int n = wn*64 + j*16 + (lane&15);
        int bbyte = (n*128 + kb*2) ^ ((n & 7) << 4);
        bf16x8 bv = __builtin_bit_cast(bf16x8, *(const u16x8*)((const char*)lB + bbyte));
        acc[0][j] = __builtin_amdgcn_mfma_f32_16x16x32_bf16(a0, bv, acc[0][j], 0, 0, 0);
        acc[1][j] = __builtin_amdgcn_mfma_f32_16x16x32_bf16(a1, bv, acc[1][j], 0, 0, 0);
      }
    }
  }
  const int ln15 = lane & 15, lq = lane >> 4;
  #pragma unroll
  for (int mf = 0; mf < 2; ++mf){
    int rowb = m0 + wm*32 + mf*16 + lq*4;
    #pragma unroll
    for (int j = 0; j < 4; ++j){
      int d = wn*64 + j*16 + ln15;
      float bo = b_og[h*Dd + d];
      #pragma unroll
      for (int r = 0; r < 4; ++r){
        size_t oi = (size_t)(rowb + r)*ROWSTR + h*Dd + d;
        float cell = out[oi];
        out[oi] = sigf(acc[mf][j][r] + bo) * cell;
      }
    }
  }
}

extern "C" void kernel_launch(void* const* d_in, const int* in_sizes, int n_in,
                              void* d_out, int out_size, void* d_ws, size_t ws_size,
                              hipStream_t stream){
  const float* x       = (const float*)d_in[0];
  const float* w_hid   = (const float*)d_in[1];
  const float* b_hid   = (const float*)d_in[2];
  const float* w_og    = (const float*)d_in[3];
  const float* b_og    = (const float*)d_in[4];
  const float* ln_g    = (const float*)d_in[5];
  const float* ln_b    = (const float*)d_in[6];
  const float* init_cx = (const float*)d_in[7];
  float* out = (float*)d_out;

  char* ws = (char*)d_ws;
  unsigned short* csum = (unsigned short*)(ws);                      // 64 MiB
  unsigned int*   fu   = (unsigned int*)  (ws + ((size_t)64  << 20)); // 128 MiB
  float*          tot  = (float*)         (ws + ((size_t)192 << 20)); // 1 MiB
  float*          Fc   = (float*)         (ws + ((size_t)193 << 20)); // 1 MiB
  float*          Cc   = (float*)         (ws + ((size_t)194 << 20)); // 1 MiB
  float2*         mr   = (float2*)        (ws + ((size_t)195 << 20)); // 128 KiB
  unsigned short* wht  = (unsigned short*)(ws + ((size_t)196 << 20)); // 3 MiB
  unsigned short* wot  = (unsigned short*)(ws + ((size_t)199 << 20)); // 1 MiB

  k_conv_whid<<<2048, 256, 0, stream>>>(w_hid, wht);
  k_conv_wog <<<1024, 256, 0, stream>>>(w_og,  wot);
  k_cumsum_a <<<Bb*Hh*NCH, Aa, 0, stream>>>(x, tot);
  k_cumsum_c <<<Bb*Hh*NCH, Aa, 0, stream>>>(x, tot, csum);
  k_stats    <<<ROWS, 256, 0, stream>>>(csum, mr);
  k_gates    <<<dim3(ROWS/128, Hh), 512, 0, stream>>>(x, csum, mr, ln_g, ln_b, wht, b_hid, fu);
  k_recur_a  <<<Bb*Hh*NCH, Dd, 0, stream>>>(fu, Fc, Cc);
  k_recur_c  <<<Bb*Hh*NCH, Dd, 0, stream>>>(fu, Fc, Cc, init_cx, out);
  k_og       <<<dim3(ROWS/128, Hh), 512, 0, stream>>>(x, wot, b_og, out);
}

// Round 3
// 662.068 us; speedup vs baseline: 1.0305x; 1.0305x over previous
//
#include <hip/hip_runtime.h>
#include <stdint.h>

#define Bb 8
#define Ss 2048
#define Hh 16
#define Aa 128
#define Dd 128
#define NGATE 384
#define KDIM 256
#define NCH 16
#define CLEN 128
#define ROWS (Bb*Ss)          // 16384 (b,s) rows
#define ROWSTR (Hh*Aa)        // 2048 elements per (b,s) row

typedef float f32x4 __attribute__((ext_vector_type(4)));
typedef __bf16 bf16x8 __attribute__((ext_vector_type(8)));
typedef unsigned short u16x8 __attribute__((ext_vector_type(8)));

static __device__ __forceinline__ unsigned short f2bf(float f){
  unsigned int u = __builtin_bit_cast(unsigned int, f);
  u += 0x7FFFu + ((u >> 16) & 1u);
  return (unsigned short)(u >> 16);
}
static __device__ __forceinline__ float bf2f(unsigned short s){
  unsigned int u = ((unsigned int)s) << 16;
  return __builtin_bit_cast(float, u);
}
static __device__ __forceinline__ float sigf(float x){ return 1.0f/(1.0f + __expf(-x)); }

// ---- weight conversion: fp32 -> bf16, [h][kk-tile] XOR-swizzled physical layout ----
// logical (n,kl) in a [N][64] bf16 tile -> byte L = n*128+kl*2 -> physical P = L ^ ((n&7)<<4)
__global__ void k_conv_whid(const float* __restrict__ w, unsigned short* __restrict__ wt){
  int idx = blockIdx.x*256 + threadIdx.x;
  const int total = Hh*KDIM*NGATE;
  for (; idx < total; idx += gridDim.x*256){
    int o = idx % NGATE; int k = (idx/NGATE) % KDIM; int h = idx/(NGATE*KDIM);
    int g = o >> 7, d = o & 127;                     // gate, channel
    int n = (d >> 4)*48 + g*16 + (d & 15);           // interleave (ig,fg,hd) per 16-col block
    int kk = k >> 6, kl = k & 63;
    int L = n*128 + kl*2;
    int P = L ^ ((n & 7) << 4);
    wt[(size_t)h*(NGATE*KDIM) + kk*(NGATE*64) + (P>>1)] = f2bf(w[idx]);
  }
}
__global__ void k_conv_wog(const float* __restrict__ w, unsigned short* __restrict__ wt){
  int idx = blockIdx.x*256 + threadIdx.x;
  const int total = Hh*KDIM*Dd;
  for (; idx < total; idx += gridDim.x*256){
    int o = idx % Dd; int k = (idx/Dd) % KDIM; int h = idx/(Dd*KDIM);
    int kk = k >> 6, kl = k & 63;
    int L = o*128 + kl*2;
    int P = L ^ ((o & 7) << 4);
    wt[(size_t)h*(Dd*KDIM) + kk*(Dd*64) + (P>>1)] = f2bf(w[idx]);
  }
}

// ---- cumsum pass A: chunk totals ----
__global__ void k_cumsum_a(const float* __restrict__ x, float* __restrict__ totals){
  int c = blockIdx.x;                       // ((b*Hh+h)*NCH + k)
  int k = c % NCH; int hb = c / NCH;
  int b = hb / Hh, h = hb % Hh;
  int a = threadIdx.x;
  const float* p = x + ((size_t)(b*Ss + k*CLEN)*Hh + h)*Aa + a;
  float run = 0.f;
  #pragma unroll 4
  for (int i = 0; i < CLEN; ++i) run += p[(size_t)i*ROWSTR];
  totals[(size_t)c*Aa + a] = run;
}

// ---- cumsum pass C: carry-in + write bf16 csum AND bf16 copy of x ----
__global__ void k_cumsum_c(const float* __restrict__ x, const float* __restrict__ totals,
                           unsigned short* __restrict__ csum, unsigned short* __restrict__ xbf){
  int c = blockIdx.x;
  int k = c % NCH; int hb = c / NCH;
  int b = hb / Hh, h = hb % Hh;
  int a = threadIdx.x;
  const float* tp = totals + (size_t)hb*NCH*Aa + a;
  float run = 0.f;
  for (int j = 0; j < k; ++j) run += tp[(size_t)j*Aa];
  const size_t base = ((size_t)(b*Ss + k*CLEN)*Hh + h)*Aa + a;
  const float* p = x + base;
  unsigned short* q  = csum + base;
  unsigned short* xq = xbf  + base;
  #pragma unroll 2
  for (int i = 0; i < CLEN; ++i){
    float v = p[(size_t)i*ROWSTR];
    run += v;
    q [(size_t)i*ROWSTR] = f2bf(run);
    xq[(size_t)i*ROWSTR] = f2bf(v);
  }
}

// ---- LN stats + apply, in place on csum (per (b,s) row over H*A = 2048) ----
__global__ void k_stats_ln(unsigned short* __restrict__ cs,
                           const float* __restrict__ ln_g, const float* __restrict__ ln_b){
  int r = blockIdx.x;
  int t = threadIdx.x;                      // 256
  unsigned short* p = cs + (size_t)r*ROWSTR + t*8;
  u16x8 v = *(const u16x8*)p;
  float s = 0.f, q = 0.f;
  #pragma unroll
  for (int i = 0; i < 8; ++i){ float f = bf2f(v[i]); s += f; q += f*f; }
  #pragma unroll
  for (int off = 32; off; off >>= 1){ s += __shfl_down(s, off); q += __shfl_down(q, off); }
  __shared__ float ls[4], lq[4];
  __shared__ float2 mrs;
  int wid = t >> 6, lane = t & 63;
  if (lane == 0){ ls[wid] = s; lq[wid] = q; }
  __syncthreads();
  if (t == 0){
    float S2 = ls[0]+ls[1]+ls[2]+ls[3], Q = lq[0]+lq[1]+lq[2]+lq[3];
    float mu = S2 * (1.0f/(float)ROWSTR);
    float var = Q * (1.0f/(float)ROWSTR) - mu*mu;
    mrs = make_float2(mu, rsqrtf(var + 1e-6f));
  }
  __syncthreads();
  float mu = mrs.x, rstd = mrs.y;
  const float4* g4 = (const float4*)(ln_g + t*8);
  const float4* b4 = (const float4*)(ln_b + t*8);
  float4 g0 = g4[0], g1 = g4[1], b0 = b4[0], b1 = b4[1];
  u16x8 o;
  o[0] = f2bf((bf2f(v[0]) - mu)*rstd*g0.x + b0.x);
  o[1] = f2bf((bf2f(v[1]) - mu)*rstd*g0.y + b0.y);
  o[2] = f2bf((bf2f(v[2]) - mu)*rstd*g0.z + b0.z);
  o[3] = f2bf((bf2f(v[3]) - mu)*rstd*g0.w + b0.w);
  o[4] = f2bf((bf2f(v[4]) - mu)*rstd*g1.x + b1.x);
  o[5] = f2bf((bf2f(v[5]) - mu)*rstd*g1.y + b1.y);
  o[6] = f2bf((bf2f(v[6]) - mu)*rstd*g1.z + b1.z);
  o[7] = f2bf((bf2f(v[7]) - mu)*rstd*g1.w + b1.w);
  *(u16x8*)p = o;
}

// ---- gates GEMM: [xbf | csln] (128x256 bf16) @ w_hid_t -> f,u packed bf16x2 ----
__launch_bounds__(512, 4)
__global__ void k_gates(const unsigned short* __restrict__ xbf,
                        const unsigned short* __restrict__ csln,
                        const unsigned short* __restrict__ wht,
                        const float* __restrict__ b_hid, unsigned int* __restrict__ fu){
  __shared__ unsigned short lA[128*64];         // 16 KiB, XOR-swizzled
  __shared__ unsigned short lB[NGATE*64];       // 48 KiB, pre-swizzled physical
  const int h = blockIdx.y;
  const int m0 = blockIdx.x * 128;
  const int tid = threadIdx.x;
  const int lane = tid & 63, wid = tid >> 6;
  const int wm = wid >> 1, wn = wid & 1;        // 4x2 wave grid: 32 rows x 192 cols each
  f32x4 acc[2][12];
  #pragma unroll
  for (int i = 0; i < 2; ++i)
    #pragma unroll
    for (int j = 0; j < 12; ++j) acc[i][j] = (f32x4){0.f,0.f,0.f,0.f};

  const int r0 = tid >> 3,          s0 = tid & 7;          // A chunk 0
  const int r1 = (tid + 512) >> 3,  s1 = tid & 7;          // A chunk 1
  const u16x8* bsrc = (const u16x8*)(wht + (size_t)h*(NGATE*KDIM));

  for (int kk = 0; kk < 4; ++kk){
    __syncthreads();
    // B: linear copy of pre-swizzled 48 KiB tile (L2/L3-cached weight reads)
    const u16x8* bs = bsrc + kk*(NGATE*64/8);
    u16x8 b0 = bs[tid], b1 = bs[tid+512], b2 = bs[tid+1024],
          b3 = bs[tid+1536], b4 = bs[tid+2048], b5 = bs[tid+2560];
    // A: two 16B chunks from bf16 source (no conversion)
    const unsigned short* as = (kk < 2) ? xbf : csln;
    const int coff = (kk & 1) * 64;
    u16x8 a0 = *(const u16x8*)(as + (size_t)(m0+r0)*ROWSTR + h*Aa + coff + s0*8);
    u16x8 a1 = *(const u16x8*)(as + (size_t)(m0+r1)*ROWSTR + h*Aa + coff + s1*8);
    u16x8* lb8 = (u16x8*)lB;
    lb8[tid] = b0; lb8[tid+512] = b1; lb8[tid+1024] = b2;
    lb8[tid+1536] = b3; lb8[tid+2048] = b4; lb8[tid+2560] = b5;
    *(u16x8*)((char*)lA + ((tid*16)        ^ ((r0 & 7) << 4))) = a0;
    *(u16x8*)((char*)lA + (((tid+512)*16)  ^ ((r1 & 7) << 4))) = a1;
    __syncthreads();
    #pragma unroll
    for (int ks = 0; ks < 2; ++ks){
      const int kb = ks*32 + (lane >> 4)*8;     // element offset in 64-col tile
      const int ra = wm*32 + (lane & 15);
      bf16x8 af0 = __builtin_bit_cast(bf16x8,
        *(const u16x8*)((const char*)lA + ((ra*128 + kb*2) ^ ((ra & 7) << 4))));
      bf16x8 af1 = __builtin_bit_cast(bf16x8,
        *(const u16x8*)((const char*)lA + (((ra+16)*128 + kb*2) ^ ((ra & 7) << 4))));
      #pragma unroll
      for (int j = 0; j < 12; ++j){
        int n = wn*192 + j*16 + (lane & 15);
        bf16x8 bv = __builtin_bit_cast(bf16x8,
          *(const u16x8*)((const char*)lB + ((n*128 + kb*2) ^ ((n & 7) << 4))));
        acc[0][j] = __builtin_amdgcn_mfma_f32_16x16x32_bf16(af0, bv, acc[0][j], 0, 0, 0);
        acc[1][j] = __builtin_amdgcn_mfma_f32_16x16x32_bf16(af1, bv, acc[1][j], 0, 0, 0);
      }
    }
  }
  // epilogue: sigmoid/relu pointwise, pack (u,f) as 2xbf16
  const int ln15 = lane & 15, lq = lane >> 4;
  #pragma unroll
  for (int mf = 0; mf < 2; ++mf){
    int rowb = m0 + wm*32 + mf*16 + lq*4;
    #pragma unroll
    for (int tb = 0; tb < 4; ++tb){
      int d = (wn*4 + tb)*16 + ln15;
      float big = b_hid[h*NGATE + d];
      float bfg = b_hid[h*NGATE + 128 + d];
      float bhd = b_hid[h*NGATE + 256 + d];
      f32x4 aig = acc[mf][tb*3+0];
      f32x4 afg = acc[mf][tb*3+1];
      f32x4 ahd = acc[mf][tb*3+2];
      #pragma unroll
      for (int r = 0; r < 4; ++r){
        float fg = sigf(afg[r] + bfg);
        float uu = sigf(aig[r] + big) * fmaxf(ahd[r] + bhd, 0.0f);
        fu[(size_t)(rowb + r)*ROWSTR + h*Dd + d] =
          ((unsigned int)f2bf(uu) << 16) | (unsigned int)f2bf(fg);
      }
    }
  }
}

// ---- recurrence pass A: per-chunk (F, C) summaries ----
__global__ void k_recur_a(const unsigned int* __restrict__ fu,
                          float* __restrict__ Fc, float* __restrict__ Cc){
  int c = blockIdx.x;
  int k = c % NCH; int hb = c / NCH;
  int b = hb / Hh, h = hb % Hh;
  int d = threadIdx.x;
  const unsigned int* p = fu + ((size_t)(b*Ss + k*CLEN)*Hh + h)*Dd + d;
  float F = 1.f, C = 0.f;
  #pragma unroll 4
  for (int i = 0; i < CLEN; ++i){
    unsigned int v = p[(size_t)i*ROWSTR];
    float f = bf2f((unsigned short)v);
    float u = bf2f((unsigned short)(v >> 16));
    C = fmaf(f, C, u);
    F *= f;
  }
  Fc[(size_t)c*Dd + d] = F;
  Cc[(size_t)c*Dd + d] = C;
}

// ---- recurrence pass C: carry-in + write cell fp32 (out) and bf16 (cellbf) ----
__global__ void k_recur_c(const unsigned int* __restrict__ fu, const float* __restrict__ Fc,
                          const float* __restrict__ Cc, const float* __restrict__ init_cx,
                          float* __restrict__ out, unsigned short* __restrict__ cellbf){
  int c = blockIdx.x;
  int k = c % NCH; int hb = c / NCH;
  int b = hb / Hh, h = hb % Hh;
  int d = threadIdx.x;
  float carry = init_cx[h*Dd + d];
  const float* fp = Fc + (size_t)hb*NCH*Dd + d;
  const float* cp = Cc + (size_t)hb*NCH*Dd + d;
  for (int j = 0; j < k; ++j) carry = fmaf(fp[(size_t)j*Dd], carry, cp[(size_t)j*Dd]);
  const size_t base = ((size_t)(b*Ss + k*CLEN)*Hh + h)*Dd + d;
  const unsigned int* p = fu + base;
  float* q = out + base;
  unsigned short* cb = cellbf + base;
  #pragma unroll 2
  for (int i = 0; i < CLEN; ++i){
    unsigned int v = p[(size_t)i*ROWSTR];
    float f = bf2f((unsigned short)v);
    float u = bf2f((unsigned short)(v >> 16));
    carry = fmaf(f, carry, u);
    q [(size_t)i*ROWSTR] = carry;
    cb[(size_t)i*ROWSTR] = f2bf(carry);
  }
}

// ---- og GEMM: [xbf | cellbf] @ w_og_t -> sigmoid -> out = og*cell (in-place) ----
__launch_bounds__(512, 4)
__global__ void k_og(const unsigned short* __restrict__ xbf,
                     const unsigned short* __restrict__ cellbf,
                     const unsigned short* __restrict__ wot,
                     const float* __restrict__ b_og, float* __restrict__ out){
  __shared__ unsigned short lA[128*64];         // 16 KiB
  __shared__ unsigned short lB[Dd*64];          // 16 KiB, pre-swizzled
  const int h = blockIdx.y;
  const int m0 = blockIdx.x * 128;
  const int tid = threadIdx.x;
  const int lane = tid & 63, wid = tid >> 6;
  const int wm = wid >> 1, wn = wid & 1;        // 4x2: 32 rows x 64 cols per wave
  f32x4 acc[2][4];
  #pragma unroll
  for (int i = 0; i < 2; ++i)
    #pragma unroll
    for (int j = 0; j < 4; ++j) acc[i][j] = (f32x4){0.f,0.f,0.f,0.f};

  const int r0 = tid >> 3,          s0 = tid & 7;
  const int r1 = (tid + 512) >> 3,  s1 = tid & 7;
  const u16x8* bsrc = (const u16x8*)(wot + (size_t)h*(Dd*KDIM));

  for (int kk = 0; kk < 4; ++kk){
    __syncthreads();
    const u16x8* bs = bsrc + kk*(Dd*64/8);
    u16x8 b0 = bs[tid], b1 = bs[tid+512];
    const unsigned short* as = (kk < 2) ? xbf : cellbf;
    const int coff = (kk & 1) * 64;
    u16x8 a0 = *(const u16x8*)(as + (size_t)(m0+r0)*ROWSTR + h*Aa + coff + s0*8);
    u16x8 a1 = *(const u16x8*)(as + (size_t)(m0+r1)*ROWSTR + h*Aa + coff + s1*8);
    u16x8* lb8 = (u16x8*)lB;
    lb8[tid] = b0; lb8[tid+512] = b1;
    *(u16x8*)((char*)lA + ((tid*16)        ^ ((r0 & 7) << 4))) = a0;
    *(u16x8*)((char*)lA + (((tid+512)*16)  ^ ((r1 & 7) << 4))) = a1;
    __syncthreads();
    #pragma unroll
    for (int ks = 0; ks < 2; ++ks){
      const int kb = ks*32 + (lane >> 4)*8;
      const int ra = wm*32 + (lane & 15);
      bf16x8 af0 = __builtin_bit_cast(bf16x8,
        *(const u16x8*)((const char*)lA + ((ra*128 + kb*2) ^ ((ra & 7) << 4))));
      bf16x8 af1 = __builtin_bit_cast(bf16x8,
        *(const u16x8*)((const char*)lA + (((ra+16)*128 + kb*2) ^ ((ra & 7) << 4))));
      #pragma unroll
      for (int j = 0; j < 4; ++j){
        int n = wn*64 + j*16 + (lane & 15);
        bf16x8 bv = __builtin_bit_cast(bf16x8,
          *(const u16x8*)((const char*)lB + ((n*128 + kb*2) ^ ((n & 7) << 4))));
        acc[0][j] = __builtin_amdgcn_mfma_f32_16x16x32_bf16(af0, bv, acc[0][j], 0, 0, 0);
        acc[1][j] = __builtin_amdgcn_mfma_f32_16x16x32_bf16(af1, bv, acc[1][j], 0, 0, 0);
      }
    }
  }
  const int ln15 = lane & 15, lq = lane >> 4;
  #pragma unroll
  for (int mf = 0; mf < 2; ++mf){
    int rowb = m0 + wm*32 + mf*16 + lq*4;
    #pragma unroll
    for (int j = 0; j < 4; ++j){
      int d = wn*64 + j*16 + ln15;
      float bo = b_og[h*Dd + d];
      #pragma unroll
      for (int r = 0; r < 4; ++r){
        size_t oi = (size_t)(rowb + r)*ROWSTR + h*Dd + d;
        float cell = out[oi];
        out[oi] = sigf(acc[mf][j][r] + bo) * cell;
      }
    }
  }
}

extern "C" void kernel_launch(void* const* d_in, const int* in_sizes, int n_in,
                              void* d_out, int out_size, void* d_ws, size_t ws_size,
                              hipStream_t stream){
  const float* x       = (const float*)d_in[0];
  const float* w_hid   = (const float*)d_in[1];
  const float* b_hid   = (const float*)d_in[2];
  const float* w_og    = (const float*)d_in[3];
  const float* b_og    = (const float*)d_in[4];
  const float* ln_g    = (const float*)d_in[5];
  const float* ln_b    = (const float*)d_in[6];
  const float* init_cx = (const float*)d_in[7];
  float* out = (float*)d_out;

  char* ws = (char*)d_ws;
  unsigned short* csum = (unsigned short*)(ws);                       // 64 MiB (csum -> csln -> cellbf)
  unsigned int*   fu   = (unsigned int*)  (ws + ((size_t)64  << 20)); // 128 MiB
  unsigned short* xbf  = (unsigned short*)(ws + ((size_t)192 << 20)); // 64 MiB
  float*          tot  = (float*)         (ws + ((size_t)256 << 20)); // 1 MiB
  float*          Fc   = (float*)         (ws + ((size_t)257 << 20)); // 1 MiB
  float*          Cc   = (float*)         (ws + ((size_t)258 << 20)); // 1 MiB
  unsigned short* wht  = (unsigned short*)(ws + ((size_t)259 << 20)); // 3 MiB
  unsigned short* wot  = (unsigned short*)(ws + ((size_t)262 << 20)); // 1 MiB
  unsigned short* cellbf = csum;   // csln dead after k_gates; reuse for bf16 cell

  k_conv_whid<<<2048, 256, 0, stream>>>(w_hid, wht);
  k_conv_wog <<<1024, 256, 0, stream>>>(w_og,  wot);
  k_cumsum_a <<<Bb*Hh*NCH, Aa, 0, stream>>>(x, tot);
  k_cumsum_c <<<Bb*Hh*NCH, Aa, 0, stream>>>(x, tot, csum, xbf);
  k_stats_ln <<<ROWS, 256, 0, stream>>>(csum, ln_g, ln_b);
  k_gates    <<<dim3(ROWS/128, Hh), 512, 0, stream>>>(xbf, csum, wht, b_hid, fu);
  k_recur_a  <<<Bb*Hh*NCH, Dd, 0, stream>>>(fu, Fc, Cc);
  k_recur_c  <<<Bb*Hh*NCH, Dd, 0, stream>>>(fu, Fc, Cc, init_cx, out, cellbf);
  k_og       <<<dim3(ROWS/128, Hh), 512, 0, stream>>>(xbf, cellbf, wot, b_og, out);
}

// Round 4
// 640.629 us; speedup vs baseline: 1.0650x; 1.0335x over previous
//
#include <hip/hip_runtime.h>
#include <stdint.h>

#define Bb 8
#define Ss 2048
#define Hh 16
#define Aa 128
#define Dd 128
#define NGATE 384
#define KDIM 256
#define NCH 16
#define CLEN 128
#define ROWS (Bb*Ss)          // 16384 (b,s) rows
#define ROWSTR (Hh*Aa)        // 2048 elements per (b,s) row

typedef float f32x4 __attribute__((ext_vector_type(4)));
typedef __bf16 bf16x8 __attribute__((ext_vector_type(8)));
typedef unsigned short u16x8 __attribute__((ext_vector_type(8)));

static __device__ __forceinline__ unsigned short f2bf(float f){
  unsigned int u = __builtin_bit_cast(unsigned int, f);
  u += 0x7FFFu + ((u >> 16) & 1u);
  return (unsigned short)(u >> 16);
}
static __device__ __forceinline__ float bf2f(unsigned short s){
  unsigned int u = ((unsigned int)s) << 16;
  return __builtin_bit_cast(float, u);
}
static __device__ __forceinline__ float sigf(float x){ return 1.0f/(1.0f + __expf(-x)); }

// ---- weight conversion: fp32 -> bf16, [h][kk-tile] XOR-swizzled physical layout ----
// logical (n,kl) in a [N][64] bf16 tile -> byte L = n*128+kl*2 -> physical P = L ^ ((n&7)<<4)
__global__ void k_conv_whid(const float* __restrict__ w, unsigned short* __restrict__ wt){
  int idx = blockIdx.x*256 + threadIdx.x;
  const int total = Hh*KDIM*NGATE;
  for (; idx < total; idx += gridDim.x*256){
    int o = idx % NGATE; int k = (idx/NGATE) % KDIM; int h = idx/(NGATE*KDIM);
    int g = o >> 7, d = o & 127;                     // gate, channel
    int n = (d >> 4)*48 + g*16 + (d & 15);           // interleave (ig,fg,hd) per 16-col block
    int kk = k >> 6, kl = k & 63;
    int L = n*128 + kl*2;
    int P = L ^ ((n & 7) << 4);
    wt[(size_t)h*(NGATE*KDIM) + kk*(NGATE*64) + (P>>1)] = f2bf(w[idx]);
  }
}
__global__ void k_conv_wog(const float* __restrict__ w, unsigned short* __restrict__ wt){
  int idx = blockIdx.x*256 + threadIdx.x;
  const int total = Hh*KDIM*Dd;
  for (; idx < total; idx += gridDim.x*256){
    int o = idx % Dd; int k = (idx/Dd) % KDIM; int h = idx/(Dd*KDIM);
    int kk = k >> 6, kl = k & 63;
    int L = o*128 + kl*2;
    int P = L ^ ((o & 7) << 4);
    wt[(size_t)h*(Dd*KDIM) + kk*(Dd*64) + (P>>1)] = f2bf(w[idx]);
  }
}

// ---- cumsum pass A: chunk totals ----
__global__ void k_cumsum_a(const float* __restrict__ x, float* __restrict__ totals){
  int c = blockIdx.x;                       // ((b*Hh+h)*NCH + k)
  int k = c % NCH; int hb = c / NCH;
  int b = hb / Hh, h = hb % Hh;
  int a = threadIdx.x;
  const float* p = x + ((size_t)(b*Ss + k*CLEN)*Hh + h)*Aa + a;
  float run = 0.f;
  #pragma unroll 4
  for (int i = 0; i < CLEN; ++i) run += p[(size_t)i*ROWSTR];
  totals[(size_t)c*Aa + a] = run;
}

// ---- cumsum pass C: carry-in + write bf16 csum AND bf16 copy of x ----
__global__ void k_cumsum_c(const float* __restrict__ x, const float* __restrict__ totals,
                           unsigned short* __restrict__ csum, unsigned short* __restrict__ xbf){
  int c = blockIdx.x;
  int k = c % NCH; int hb = c / NCH;
  int b = hb / Hh, h = hb % Hh;
  int a = threadIdx.x;
  const float* tp = totals + (size_t)hb*NCH*Aa + a;
  float run = 0.f;
  for (int j = 0; j < k; ++j) run += tp[(size_t)j*Aa];
  const size_t base = ((size_t)(b*Ss + k*CLEN)*Hh + h)*Aa + a;
  const float* p = x + base;
  unsigned short* q  = csum + base;
  unsigned short* xq = xbf  + base;
  #pragma unroll 2
  for (int i = 0; i < CLEN; ++i){
    float v = p[(size_t)i*ROWSTR];
    run += v;
    q [(size_t)i*ROWSTR] = f2bf(run);
    xq[(size_t)i*ROWSTR] = f2bf(v);
  }
}

// ---- LN stats + apply, in place on csum (per (b,s) row over H*A = 2048) ----
__global__ void k_stats_ln(unsigned short* __restrict__ cs,
                           const float* __restrict__ ln_g, const float* __restrict__ ln_b){
  int r = blockIdx.x;
  int t = threadIdx.x;                      // 256
  unsigned short* p = cs + (size_t)r*ROWSTR + t*8;
  u16x8 v = *(const u16x8*)p;
  float s = 0.f, q = 0.f;
  #pragma unroll
  for (int i = 0; i < 8; ++i){ float f = bf2f(v[i]); s += f; q += f*f; }
  #pragma unroll
  for (int off = 32; off; off >>= 1){ s += __shfl_down(s, off); q += __shfl_down(q, off); }
  __shared__ float ls[4], lq[4];
  __shared__ float2 mrs;
  int wid = t >> 6, lane = t & 63;
  if (lane == 0){ ls[wid] = s; lq[wid] = q; }
  __syncthreads();
  if (t == 0){
    float S2 = ls[0]+ls[1]+ls[2]+ls[3], Q = lq[0]+lq[1]+lq[2]+lq[3];
    float mu = S2 * (1.0f/(float)ROWSTR);
    float var = Q * (1.0f/(float)ROWSTR) - mu*mu;
    mrs = make_float2(mu, rsqrtf(var + 1e-6f));
  }
  __syncthreads();
  float mu = mrs.x, rstd = mrs.y;
  const float4* g4 = (const float4*)(ln_g + t*8);
  const float4* b4 = (const float4*)(ln_b + t*8);
  float4 g0 = g4[0], g1 = g4[1], b0 = b4[0], b1 = b4[1];
  u16x8 o;
  o[0] = f2bf((bf2f(v[0]) - mu)*rstd*g0.x + b0.x);
  o[1] = f2bf((bf2f(v[1]) - mu)*rstd*g0.y + b0.y);
  o[2] = f2bf((bf2f(v[2]) - mu)*rstd*g0.z + b0.z);
  o[3] = f2bf((bf2f(v[3]) - mu)*rstd*g0.w + b0.w);
  o[4] = f2bf((bf2f(v[4]) - mu)*rstd*g1.x + b1.x);
  o[5] = f2bf((bf2f(v[5]) - mu)*rstd*g1.y + b1.y);
  o[6] = f2bf((bf2f(v[6]) - mu)*rstd*g1.z + b1.z);
  o[7] = f2bf((bf2f(v[7]) - mu)*rstd*g1.w + b1.w);
  *(u16x8*)p = o;
}

// ---- gates GEMM: [xbf | csln] (128x256 bf16) @ w_hid_t -> f,u packed bf16x2 ----
// XCD-head swizzle: XCD k (bid&7) runs only heads {2k,2k+1} -> weights L2-resident.
// Pipelined: A(kk+1) register-prefetch issued under MFMA(kk).
__launch_bounds__(512, 4)
__global__ void k_gates(const unsigned short* __restrict__ xbf,
                        const unsigned short* __restrict__ csln,
                        const unsigned short* __restrict__ wht,
                        const float* __restrict__ b_hid, unsigned int* __restrict__ fu){
  __shared__ unsigned short lA[128*64];         // 16 KiB, XOR-swizzled
  __shared__ unsigned short lB[NGATE*64];       // 48 KiB, pre-swizzled physical
  const int bid  = blockIdx.x;
  const int slot = bid >> 3;
  const int h    = (bid & 7)*2 + (slot >> 7);
  const int m0   = (slot & 127) * 128;
  const int tid = threadIdx.x;
  const int lane = tid & 63, wid = tid >> 6;
  const int wm = wid >> 1, wn = wid & 1;        // 4x2 wave grid: 32 rows x 192 cols each
  f32x4 acc[2][12];
  #pragma unroll
  for (int i = 0; i < 2; ++i)
    #pragma unroll
    for (int j = 0; j < 12; ++j) acc[i][j] = (f32x4){0.f,0.f,0.f,0.f};

  const int r0 = tid >> 3, s0 = tid & 7;        // A chunk rows r0, r0+64
  const int r1 = r0 + 64;
  const u16x8* bsrc = (const u16x8*)(wht + (size_t)h*(NGATE*KDIM));
  const size_t aoff0 = (size_t)(m0+r0)*ROWSTR + h*Aa + s0*8;
  const size_t aoff1 = (size_t)(m0+r1)*ROWSTR + h*Aa + s0*8;

  // prologue: prefetch A(kk=0)
  u16x8 pa0 = *(const u16x8*)(xbf + aoff0);
  u16x8 pa1 = *(const u16x8*)(xbf + aoff1);

  #pragma unroll
  for (int kk = 0; kk < 4; ++kk){
    // B(kk): L2-hit loads (weights XCD-resident), overlapped with A ds_writes
    const u16x8* bs = bsrc + kk*(NGATE*64/8);
    u16x8 b0 = bs[tid], b1 = bs[tid+512], b2 = bs[tid+1024],
          b3 = bs[tid+1536], b4 = bs[tid+2048], b5 = bs[tid+2560];
    *(u16x8*)((char*)lA + ((tid*16)        ^ ((r0 & 7) << 4))) = pa0;
    *(u16x8*)((char*)lA + (((tid+512)*16)  ^ ((r1 & 7) << 4))) = pa1;
    u16x8* lb8 = (u16x8*)lB;
    lb8[tid] = b0; lb8[tid+512] = b1; lb8[tid+1024] = b2;
    lb8[tid+1536] = b3; lb8[tid+2048] = b4; lb8[tid+2560] = b5;
    __syncthreads();
    if (kk < 3){                                // prefetch A(kk+1) under MFMA
      const unsigned short* as = (kk >= 1) ? csln : xbf;
      const int coff = ((kk+1) & 1) * 64;
      pa0 = *(const u16x8*)(as + aoff0 + coff);
      pa1 = *(const u16x8*)(as + aoff1 + coff);
    }
    #pragma unroll
    for (int ks = 0; ks < 2; ++ks){
      const int kb = ks*32 + (lane >> 4)*8;     // element offset in 64-col tile
      const int ra = wm*32 + (lane & 15);
      bf16x8 af0 = __builtin_bit_cast(bf16x8,
        *(const u16x8*)((const char*)lA + ((ra*128 + kb*2) ^ ((ra & 7) << 4))));
      bf16x8 af1 = __builtin_bit_cast(bf16x8,
        *(const u16x8*)((const char*)lA + (((ra+16)*128 + kb*2) ^ ((ra & 7) << 4))));
      #pragma unroll
      for (int j = 0; j < 12; ++j){
        int n = wn*192 + j*16 + (lane & 15);
        bf16x8 bv = __builtin_bit_cast(bf16x8,
          *(const u16x8*)((const char*)lB + ((n*128 + kb*2) ^ ((n & 7) << 4))));
        acc[0][j] = __builtin_amdgcn_mfma_f32_16x16x32_bf16(af0, bv, acc[0][j], 0, 0, 0);
        acc[1][j] = __builtin_amdgcn_mfma_f32_16x16x32_bf16(af1, bv, acc[1][j], 0, 0, 0);
      }
    }
    __syncthreads();
  }
  // epilogue: sigmoid/relu pointwise, pack (u,f) as 2xbf16
  const int ln15 = lane & 15, lq = lane >> 4;
  #pragma unroll
  for (int mf = 0; mf < 2; ++mf){
    int rowb = m0 + wm*32 + mf*16 + lq*4;
    #pragma unroll
    for (int tb = 0; tb < 4; ++tb){
      int d = (wn*4 + tb)*16 + ln15;
      float big = b_hid[h*NGATE + d];
      float bfg = b_hid[h*NGATE + 128 + d];
      float bhd = b_hid[h*NGATE + 256 + d];
      f32x4 aig = acc[mf][tb*3+0];
      f32x4 afg = acc[mf][tb*3+1];
      f32x4 ahd = acc[mf][tb*3+2];
      #pragma unroll
      for (int r = 0; r < 4; ++r){
        float fg = sigf(afg[r] + bfg);
        float uu = sigf(aig[r] + big) * fmaxf(ahd[r] + bhd, 0.0f);
        fu[(size_t)(rowb + r)*ROWSTR + h*Dd + d] =
          ((unsigned int)f2bf(uu) << 16) | (unsigned int)f2bf(fg);
      }
    }
  }
}

// ---- recurrence pass A: per-chunk (F, C) summaries ----
__global__ void k_recur_a(const unsigned int* __restrict__ fu,
                          float* __restrict__ Fc, float* __restrict__ Cc){
  int c = blockIdx.x;
  int k = c % NCH; int hb = c / NCH;
  int b = hb / Hh, h = hb % Hh;
  int d = threadIdx.x;
  const unsigned int* p = fu + ((size_t)(b*Ss + k*CLEN)*Hh + h)*Dd + d;
  float F = 1.f, C = 0.f;
  #pragma unroll 4
  for (int i = 0; i < CLEN; ++i){
    unsigned int v = p[(size_t)i*ROWSTR];
    float f = bf2f((unsigned short)v);
    float u = bf2f((unsigned short)(v >> 16));
    C = fmaf(f, C, u);
    F *= f;
  }
  Fc[(size_t)c*Dd + d] = F;
  Cc[(size_t)c*Dd + d] = C;
}

// ---- recurrence pass C: carry-in + write cell fp32 (out) and bf16 (cellbf) ----
__global__ void k_recur_c(const unsigned int* __restrict__ fu, const float* __restrict__ Fc,
                          const float* __restrict__ Cc, const float* __restrict__ init_cx,
                          float* __restrict__ out, unsigned short* __restrict__ cellbf){
  int c = blockIdx.x;
  int k = c % NCH; int hb = c / NCH;
  int b = hb / Hh, h = hb % Hh;
  int d = threadIdx.x;
  float carry = init_cx[h*Dd + d];
  const float* fp = Fc + (size_t)hb*NCH*Dd + d;
  const float* cp = Cc + (size_t)hb*NCH*Dd + d;
  for (int j = 0; j < k; ++j) carry = fmaf(fp[(size_t)j*Dd], carry, cp[(size_t)j*Dd]);
  const size_t base = ((size_t)(b*Ss + k*CLEN)*Hh + h)*Dd + d;
  const unsigned int* p = fu + base;
  float* q = out + base;
  unsigned short* cb = cellbf + base;
  #pragma unroll 2
  for (int i = 0; i < CLEN; ++i){
    unsigned int v = p[(size_t)i*ROWSTR];
    float f = bf2f((unsigned short)v);
    float u = bf2f((unsigned short)(v >> 16));
    carry = fmaf(f, carry, u);
    q [(size_t)i*ROWSTR] = carry;
    cb[(size_t)i*ROWSTR] = f2bf(carry);
  }
}

// ---- og GEMM: [xbf | cellbf] @ w_og_t -> sigmoid -> out = og*cell (in-place) ----
__launch_bounds__(512, 4)
__global__ void k_og(const unsigned short* __restrict__ xbf,
                     const unsigned short* __restrict__ cellbf,
                     const unsigned short* __restrict__ wot,
                     const float* __restrict__ b_og, float* __restrict__ out){
  __shared__ unsigned short lA[128*64];         // 16 KiB
  __shared__ unsigned short lB[Dd*64];          // 16 KiB, pre-swizzled
  const int bid  = blockIdx.x;
  const int slot = bid >> 3;
  const int h    = (bid & 7)*2 + (slot >> 7);
  const int m0   = (slot & 127) * 128;
  const int tid = threadIdx.x;
  const int lane = tid & 63, wid = tid >> 6;
  const int wm = wid >> 1, wn = wid & 1;        // 4x2: 32 rows x 64 cols per wave
  f32x4 acc[2][4];
  #pragma unroll
  for (int i = 0; i < 2; ++i)
    #pragma unroll
    for (int j = 0; j < 4; ++j) acc[i][j] = (f32x4){0.f,0.f,0.f,0.f};

  const int r0 = tid >> 3, s0 = tid & 7;
  const int r1 = r0 + 64;
  const u16x8* bsrc = (const u16x8*)(wot + (size_t)h*(Dd*KDIM));
  const size_t aoff0 = (size_t)(m0+r0)*ROWSTR + h*Aa + s0*8;
  const size_t aoff1 = (size_t)(m0+r1)*ROWSTR + h*Aa + s0*8;

  u16x8 pa0 = *(const u16x8*)(xbf + aoff0);
  u16x8 pa1 = *(const u16x8*)(xbf + aoff1);

  #pragma unroll
  for (int kk = 0; kk < 4; ++kk){
    const u16x8* bs = bsrc + kk*(Dd*64/8);
    u16x8 b0 = bs[tid], b1 = bs[tid+512];
    *(u16x8*)((char*)lA + ((tid*16)        ^ ((r0 & 7) << 4))) = pa0;
    *(u16x8*)((char*)lA + (((tid+512)*16)  ^ ((r1 & 7) << 4))) = pa1;
    u16x8* lb8 = (u16x8*)lB;
    lb8[tid] = b0; lb8[tid+512] = b1;
    __syncthreads();
    if (kk < 3){
      const unsigned short* as = (kk >= 1) ? cellbf : xbf;
      const int coff = ((kk+1) & 1) * 64;
      pa0 = *(const u16x8*)(as + aoff0 + coff);
      pa1 = *(const u16x8*)(as + aoff1 + coff);
    }
    #pragma unroll
    for (int ks = 0; ks < 2; ++ks){
      const int kb = ks*32 + (lane >> 4)*8;
      const int ra = wm*32 + (lane & 15);
      bf16x8 af0 = __builtin_bit_cast(bf16x8,
        *(const u16x8*)((const char*)lA + ((ra*128 + kb*2) ^ ((ra & 7) << 4))));
      bf16x8 af1 = __builtin_bit_cast(bf16x8,
        *(const u16x8*)((const char*)lA + (((ra+16)*128 + kb*2) ^ ((ra & 7) << 4))));
      #pragma unroll
      for (int j = 0; j < 4; ++j){
        int n = wn*64 + j*16 + (lane & 15);
        bf16x8 bv = __builtin_bit_cast(bf16x8,
          *(const u16x8*)((const char*)lB + ((n*128 + kb*2) ^ ((n & 7) << 4))));
        acc[0][j] = __builtin_amdgcn_mfma_f32_16x16x32_bf16(af0, bv, acc[0][j], 0, 0, 0);
        acc[1][j] = __builtin_amdgcn_mfma_f32_16x16x32_bf16(af1, bv, acc[1][j], 0, 0, 0);
      }
    }
    __syncthreads();
  }
  const int ln15 = lane & 15, lq = lane >> 4;
  #pragma unroll
  for (int mf = 0; mf < 2; ++mf){
    int rowb = m0 + wm*32 + mf*16 + lq*4;
    #pragma unroll
    for (int j = 0; j < 4; ++j){
      int d = wn*64 + j*16 + ln15;
      float bo = b_og[h*Dd + d];
      #pragma unroll
      for (int r = 0; r < 4; ++r){
        size_t oi = (size_t)(rowb + r)*ROWSTR + h*Dd + d;
        float cell = out[oi];
        out[oi] = sigf(acc[mf][j][r] + bo) * cell;
      }
    }
  }
}

extern "C" void kernel_launch(void* const* d_in, const int* in_sizes, int n_in,
                              void* d_out, int out_size, void* d_ws, size_t ws_size,
                              hipStream_t stream){
  const float* x       = (const float*)d_in[0];
  const float* w_hid   = (const float*)d_in[1];
  const float* b_hid   = (const float*)d_in[2];
  const float* w_og    = (const float*)d_in[3];
  const float* b_og    = (const float*)d_in[4];
  const float* ln_g    = (const float*)d_in[5];
  const float* ln_b    = (const float*)d_in[6];
  const float* init_cx = (const float*)d_in[7];
  float* out = (float*)d_out;

  char* ws = (char*)d_ws;
  unsigned short* csum = (unsigned short*)(ws);                       // 64 MiB (csum -> csln -> cellbf)
  unsigned int*   fu   = (unsigned int*)  (ws + ((size_t)64  << 20)); // 128 MiB
  unsigned short* xbf  = (unsigned short*)(ws + ((size_t)192 << 20)); // 64 MiB
  float*          tot  = (float*)         (ws + ((size_t)256 << 20)); // 1 MiB
  float*          Fc   = (float*)         (ws + ((size_t)257 << 20)); // 1 MiB
  float*          Cc   = (float*)         (ws + ((size_t)258 << 20)); // 1 MiB
  unsigned short* wht  = (unsigned short*)(ws + ((size_t)259 << 20)); // 3 MiB
  unsigned short* wot  = (unsigned short*)(ws + ((size_t)262 << 20)); // 1 MiB
  unsigned short* cellbf = csum;   // csln dead after k_gates; reuse for bf16 cell

  k_conv_whid<<<2048, 256, 0, stream>>>(w_hid, wht);
  k_conv_wog <<<1024, 256, 0, stream>>>(w_og,  wot);
  k_cumsum_a <<<Bb*Hh*NCH, Aa, 0, stream>>>(x, tot);
  k_cumsum_c <<<Bb*Hh*NCH, Aa, 0, stream>>>(x, tot, csum, xbf);
  k_stats_ln <<<ROWS, 256, 0, stream>>>(csum, ln_g, ln_b);
  k_gates    <<<(ROWS/128)*Hh, 512, 0, stream>>>(xbf, csum, wht, b_hid, fu);
  k_recur_a  <<<Bb*Hh*NCH, Dd, 0, stream>>>(fu, Fc, Cc);
  k_recur_c  <<<Bb*Hh*NCH, Dd, 0, stream>>>(fu, Fc, Cc, init_cx, out, cellbf);
  k_og       <<<(ROWS/128)*Hh, 512, 0, stream>>>(xbf, cellbf, wot, b_og, out);
}

// Round 5
// 453.004 us; speedup vs baseline: 1.5061x; 1.4142x over previous
//
#include <hip/hip_runtime.h>
#include <stdint.h>

#define Bb 8
#define Ss 2048
#define Hh 16
#define Aa 128
#define Dd 128
#define NGATE 384
#define KDIM 256
#define NCH 16
#define CLEN 128
#define ROWS (Bb*Ss)          // 16384 (b,s) rows
#define ROWSTR (Hh*Aa)        // 2048 elements per (b,s) row

typedef float f32x4 __attribute__((ext_vector_type(4)));
typedef __bf16 bf16x8 __attribute__((ext_vector_type(8)));
typedef unsigned short u16x8 __attribute__((ext_vector_type(8)));

static __device__ __forceinline__ unsigned short f2bf(float f){
  unsigned int u = __builtin_bit_cast(unsigned int, f);
  u += 0x7FFFu + ((u >> 16) & 1u);
  return (unsigned short)(u >> 16);
}
static __device__ __forceinline__ float bf2f(unsigned short s){
  unsigned int u = ((unsigned int)s) << 16;
  return __builtin_bit_cast(float, u);
}
static __device__ __forceinline__ float sigf(float x){ return 1.0f/(1.0f + __expf(-x)); }

// ---- weight conversion ----
// w_hid -> per head, two 192-col N-halves, [n_loc][k] bf16, XOR-swizzled:
//   byte P = (n_loc*512 + k*2) ^ ((n_loc&7)<<4)
__global__ void k_conv_whid(const float* __restrict__ w, unsigned short* __restrict__ wt){
  int idx = blockIdx.x*256 + threadIdx.x;
  const int total = Hh*KDIM*NGATE;
  for (; idx < total; idx += gridDim.x*256){
    int o = idx % NGATE; int k = (idx/NGATE) % KDIM; int h = idx/(NGATE*KDIM);
    int g = o >> 7, d = o & 127;                     // gate, channel
    int nh = d >> 6, dl = d & 63;
    int n = (dl >> 4)*48 + g*16 + (d & 15);          // interleave (ig,fg,hd) per 16-ch block
    int P = (n*512 + k*2) ^ ((n & 7) << 4);
    wt[(size_t)h*(NGATE*KDIM) + nh*(192*KDIM) + (P>>1)] = f2bf(w[idx]);
  }
}
// w_og -> per head [o][k] bf16, swizzled: P = (o*512 + k*2) ^ ((o&7)<<4)
__global__ void k_conv_wog(const float* __restrict__ w, unsigned short* __restrict__ wt){
  int idx = blockIdx.x*256 + threadIdx.x;
  const int total = Hh*KDIM*Dd;
  for (; idx < total; idx += gridDim.x*256){
    int o = idx % Dd; int k = (idx/Dd) % KDIM; int h = idx/(Dd*KDIM);
    int P = (o*512 + k*2) ^ ((o & 7) << 4);
    wt[(size_t)h*(Dd*KDIM) + (P>>1)] = f2bf(w[idx]);
  }
}

// ---- cumsum pass A: chunk totals ----
__global__ void k_cumsum_a(const float* __restrict__ x, float* __restrict__ totals){
  int c = blockIdx.x;                       // ((b*Hh+h)*NCH + k)
  int k = c % NCH; int hb = c / NCH;
  int b = hb / Hh, h = hb % Hh;
  int a = threadIdx.x;
  const float* p = x + ((size_t)(b*Ss + k*CLEN)*Hh + h)*Aa + a;
  float run = 0.f;
  #pragma unroll 4
  for (int i = 0; i < CLEN; ++i) run += p[(size_t)i*ROWSTR];
  totals[(size_t)c*Aa + a] = run;
}

// ---- cumsum pass C: carry-in + write bf16 csum AND bf16 copy of x ----
__global__ void k_cumsum_c(const float* __restrict__ x, const float* __restrict__ totals,
                           unsigned short* __restrict__ csum, unsigned short* __restrict__ xbf){
  int c = blockIdx.x;
  int k = c % NCH; int hb = c / NCH;
  int b = hb / Hh, h = hb % Hh;
  int a = threadIdx.x;
  const float* tp = totals + (size_t)hb*NCH*Aa + a;
  float run = 0.f;
  for (int j = 0; j < k; ++j) run += tp[(size_t)j*Aa];
  const size_t base = ((size_t)(b*Ss + k*CLEN)*Hh + h)*Aa + a;
  const float* p = x + base;
  unsigned short* q  = csum + base;
  unsigned short* xq = xbf  + base;
  #pragma unroll 2
  for (int i = 0; i < CLEN; ++i){
    float v = p[(size_t)i*ROWSTR];
    run += v;
    q [(size_t)i*ROWSTR] = f2bf(run);
    xq[(size_t)i*ROWSTR] = f2bf(v);
  }
}

// ---- LN stats + apply, in place on csum (per (b,s) row over H*A = 2048) ----
__global__ void k_stats_ln(unsigned short* __restrict__ cs,
                           const float* __restrict__ ln_g, const float* __restrict__ ln_b){
  int r = blockIdx.x;
  int t = threadIdx.x;                      // 256
  unsigned short* p = cs + (size_t)r*ROWSTR + t*8;
  u16x8 v = *(const u16x8*)p;
  float s = 0.f, q = 0.f;
  #pragma unroll
  for (int i = 0; i < 8; ++i){ float f = bf2f(v[i]); s += f; q += f*f; }
  #pragma unroll
  for (int off = 32; off; off >>= 1){ s += __shfl_down(s, off); q += __shfl_down(q, off); }
  __shared__ float ls[4], lq[4];
  __shared__ float2 mrs;
  int wid = t >> 6, lane = t & 63;
  if (lane == 0){ ls[wid] = s; lq[wid] = q; }
  __syncthreads();
  if (t == 0){
    float S2 = ls[0]+ls[1]+ls[2]+ls[3], Q = lq[0]+lq[1]+lq[2]+lq[3];
    float mu = S2 * (1.0f/(float)ROWSTR);
    float var = Q * (1.0f/(float)ROWSTR) - mu*mu;
    mrs = make_float2(mu, rsqrtf(var + 1e-6f));
  }
  __syncthreads();
  float mu = mrs.x, rstd = mrs.y;
  const float4* g4 = (const float4*)(ln_g + t*8);
  const float4* b4 = (const float4*)(ln_b + t*8);
  float4 g0 = g4[0], g1 = g4[1], b0 = b4[0], b1 = b4[1];
  u16x8 o;
  o[0] = f2bf((bf2f(v[0]) - mu)*rstd*g0.x + b0.x);
  o[1] = f2bf((bf2f(v[1]) - mu)*rstd*g0.y + b0.y);
  o[2] = f2bf((bf2f(v[2]) - mu)*rstd*g0.z + b0.z);
  o[3] = f2bf((bf2f(v[3]) - mu)*rstd*g0.w + b0.w);
  o[4] = f2bf((bf2f(v[4]) - mu)*rstd*g1.x + b1.x);
  o[5] = f2bf((bf2f(v[5]) - mu)*rstd*g1.y + b1.y);
  o[6] = f2bf((bf2f(v[6]) - mu)*rstd*g1.z + b1.z);
  o[7] = f2bf((bf2f(v[7]) - mu)*rstd*g1.w + b1.w);
  *(u16x8*)p = o;
}

// ---- gates GEMM v3: B-half (192x256) resident in LDS; A double-buffered ----
// grid (8, 32): x = m-group, y = h*2 + nhalf. 512 thr, 8 waves (4m x 2n).
#define GNT 16   // M-tiles per block (16384/8/128)
__launch_bounds__(512)
__global__ void k_gates(const unsigned short* __restrict__ xbf,
                        const unsigned short* __restrict__ csln,
                        const unsigned short* __restrict__ wht,
                        const float* __restrict__ b_hid, unsigned int* __restrict__ fu){
  __shared__ unsigned short lB[192*KDIM];       // 96 KiB, pre-swizzled
  __shared__ unsigned short lA[2][128*64];      // 2 x 16 KiB
  const int mg = blockIdx.x;
  const int h  = blockIdx.y >> 1, nh = blockIdx.y & 1;
  const int tid = threadIdx.x;
  const int lane = tid & 63, wid = tid >> 6;
  const int wm = wid >> 1, wn = wid & 1;        // 4x2 waves: 32 rows x 96 cols each
  const int ln15 = lane & 15, lq = lane >> 4;

  // B once: 96 KiB = 6144 x 16B, 12 chunks/thread, linear (pre-swizzled)
  {
    const u16x8* bs = (const u16x8*)(wht + (size_t)h*(NGATE*KDIM) + nh*(192*KDIM));
    u16x8* lb8 = (u16x8*)lB;
    #pragma unroll
    for (int i = 0; i < 12; ++i) lb8[tid + i*512] = bs[tid + i*512];
  }
  // A staging geometry: chunks c=tid, tid+512; row=c>>3, col16=(c&7)
  const int r0 = tid >> 3, q0 = tid & 7;        // rows r0, r0+64
  const int lw0 = (r0*128 + q0*16) ^ ((r0 & 7) << 4);
  const int lw1 = ((r0+64)*128 + q0*16) ^ (((r0+64) & 7) << 4);

  #define GA_LOAD(pa, pb, t_, kk_) do { \
    const unsigned short* as_ = ((kk_) < 2) ? xbf : csln; \
    const int co_ = ((kk_) & 1) * 64; \
    const size_t b0_ = (size_t)(((mg*GNT + (t_))*128) + r0)*ROWSTR + h*Aa + co_ + q0*8; \
    pa = *(const u16x8*)(as_ + b0_); \
    pb = *(const u16x8*)(as_ + b0_ + (size_t)64*ROWSTR); \
  } while(0)

  f32x4 acc[2][6];
  #pragma unroll
  for (int i = 0; i < 2; ++i)
    #pragma unroll
    for (int j = 0; j < 6; ++j) acc[i][j] = (f32x4){0.f,0.f,0.f,0.f};

  u16x8 pa0, pa1;
  // prologue: stage p=0 into buf0, prefetch p=1
  GA_LOAD(pa0, pa1, 0, 0);
  *(u16x8*)((char*)lA[0] + lw0) = pa0;
  *(u16x8*)((char*)lA[0] + lw1) = pa1;
  GA_LOAD(pa0, pa1, 0, 1);
  __syncthreads();

  for (int t = 0; t < GNT; ++t){
    #pragma unroll
    for (int kk = 0; kk < 4; ++kk){
      const int cur = kk & 1;
      // write phase p+1 into buf[cur^1]
      if (t < GNT-1 || kk < 3){
        *(u16x8*)((char*)lA[cur^1] + lw0) = pa0;
        *(u16x8*)((char*)lA[cur^1] + lw1) = pa1;
      }
      // prefetch phase p+2
      {
        const int t2 = t + (kk >= 2);
        if (t2 < GNT){
          const int kk2 = (kk + 2) & 3;
          GA_LOAD(pa0, pa1, t2, kk2);
        }
      }
      __syncthreads();
      #pragma unroll
      for (int ks = 0; ks < 2; ++ks){
        const int kel = ks*32 + lq*8;           // element offset within 64-col A tile
        const int ra = wm*32 + ln15;
        bf16x8 af0 = __builtin_bit_cast(bf16x8,
          *(const u16x8*)((const char*)lA[cur] + ((ra*128 + kel*2) ^ ((ra & 7) << 4))));
        bf16x8 af1 = __builtin_bit_cast(bf16x8,
          *(const u16x8*)((const char*)lA[cur] + (((ra+16)*128 + kel*2) ^ (((ra+16) & 7) << 4))));
        const int kfull = kk*64 + kel;          // k within 256
        #pragma unroll
        for (int j = 0; j < 6; ++j){
          const int n = wn*96 + j*16 + ln15;
          bf16x8 bv = __builtin_bit_cast(bf16x8,
            *(const u16x8*)((const char*)lB + ((n*512 + kfull*2) ^ ((n & 7) << 4))));
          acc[0][j] = __builtin_amdgcn_mfma_f32_16x16x32_bf16(af0, bv, acc[0][j], 0, 0, 0);
          acc[1][j] = __builtin_amdgcn_mfma_f32_16x16x32_bf16(af1, bv, acc[1][j], 0, 0, 0);
        }
      }
      __syncthreads();
    }
    // epilogue for tile t
    const int m0 = (mg*GNT + t)*128;
    #pragma unroll
    for (int mf = 0; mf < 2; ++mf){
      const int rowb = m0 + wm*32 + mf*16 + lq*4;
      #pragma unroll
      for (int tb = 0; tb < 2; ++tb){
        const int d = nh*64 + (wn*2 + tb)*16 + ln15;
        float big = b_hid[h*NGATE + d];
        float bfg = b_hid[h*NGATE + 128 + d];
        float bhd = b_hid[h*NGATE + 256 + d];
        f32x4 aig = acc[mf][tb*3+0];
        f32x4 afg = acc[mf][tb*3+1];
        f32x4 ahd = acc[mf][tb*3+2];
        #pragma unroll
        for (int r = 0; r < 4; ++r){
          float fg = sigf(afg[r] + bfg);
          float uu = sigf(aig[r] + big) * fmaxf(ahd[r] + bhd, 0.0f);
          fu[(size_t)(rowb + r)*ROWSTR + h*Dd + d] =
            ((unsigned int)f2bf(uu) << 16) | (unsigned int)f2bf(fg);
        }
        acc[mf][tb*3+0] = (f32x4){0.f,0.f,0.f,0.f};
        acc[mf][tb*3+1] = (f32x4){0.f,0.f,0.f,0.f};
        acc[mf][tb*3+2] = (f32x4){0.f,0.f,0.f,0.f};
      }
    }
  }
  #undef GA_LOAD
}

// ---- recurrence pass A: per-chunk (F, C) summaries ----
__global__ void k_recur_a(const unsigned int* __restrict__ fu,
                          float* __restrict__ Fc, float* __restrict__ Cc){
  int c = blockIdx.x;
  int k = c % NCH; int hb = c / NCH;
  int b = hb / Hh, h = hb % Hh;
  int d = threadIdx.x;
  const unsigned int* p = fu + ((size_t)(b*Ss + k*CLEN)*Hh + h)*Dd + d;
  float F = 1.f, C = 0.f;
  #pragma unroll 4
  for (int i = 0; i < CLEN; ++i){
    unsigned int v = p[(size_t)i*ROWSTR];
    float f = bf2f((unsigned short)v);
    float u = bf2f((unsigned short)(v >> 16));
    C = fmaf(f, C, u);
    F *= f;
  }
  Fc[(size_t)c*Dd + d] = F;
  Cc[(size_t)c*Dd + d] = C;
}

// ---- recurrence pass C: carry-in + write cell fp32 (out) and bf16 (cellbf) ----
__global__ void k_recur_c(const unsigned int* __restrict__ fu, const float* __restrict__ Fc,
                          const float* __restrict__ Cc, const float* __restrict__ init_cx,
                          float* __restrict__ out, unsigned short* __restrict__ cellbf){
  int c = blockIdx.x;
  int k = c % NCH; int hb = c / NCH;
  int b = hb / Hh, h = hb % Hh;
  int d = threadIdx.x;
  float carry = init_cx[h*Dd + d];
  const float* fp = Fc + (size_t)hb*NCH*Dd + d;
  const float* cp = Cc + (size_t)hb*NCH*Dd + d;
  for (int j = 0; j < k; ++j) carry = fmaf(fp[(size_t)j*Dd], carry, cp[(size_t)j*Dd]);
  const size_t base = ((size_t)(b*Ss + k*CLEN)*Hh + h)*Dd + d;
  const unsigned int* p = fu + base;
  float* q = out + base;
  unsigned short* cb = cellbf + base;
  #pragma unroll 2
  for (int i = 0; i < CLEN; ++i){
    unsigned int v = p[(size_t)i*ROWSTR];
    float f = bf2f((unsigned short)v);
    float u = bf2f((unsigned short)(v >> 16));
    carry = fmaf(f, carry, u);
    q [(size_t)i*ROWSTR] = carry;
    cb[(size_t)i*ROWSTR] = f2bf(carry);
  }
}

// ---- og GEMM v3: full B (128x256) resident in LDS; A double-buffered ----
// grid (16, 16): x = m-group, y = h. 512 thr, 8 waves (4m x 2n).
#define ONT 8    // M-tiles per block (16384/16/128)
__launch_bounds__(512)
__global__ void k_og(const unsigned short* __restrict__ xbf,
                     const unsigned short* __restrict__ cellbf,
                     const unsigned short* __restrict__ wot,
                     const float* __restrict__ b_og, float* __restrict__ out){
  __shared__ unsigned short lB[Dd*KDIM];        // 64 KiB, pre-swizzled
  __shared__ unsigned short lA[2][128*64];      // 2 x 16 KiB
  const int mg = blockIdx.x;
  const int h  = blockIdx.y;
  const int tid = threadIdx.x;
  const int lane = tid & 63, wid = tid >> 6;
  const int wm = wid >> 1, wn = wid & 1;        // 4x2: 32 rows x 64 cols each
  const int ln15 = lane & 15, lq = lane >> 4;

  {
    const u16x8* bs = (const u16x8*)(wot + (size_t)h*(Dd*KDIM));
    u16x8* lb8 = (u16x8*)lB;
    #pragma unroll
    for (int i = 0; i < 8; ++i) lb8[tid + i*512] = bs[tid + i*512];
  }
  const int r0 = tid >> 3, q0 = tid & 7;
  const int lw0 = (r0*128 + q0*16) ^ ((r0 & 7) << 4);
  const int lw1 = ((r0+64)*128 + q0*16) ^ (((r0+64) & 7) << 4);

  #define OA_LOAD(pa, pb, t_, kk_) do { \
    const unsigned short* as_ = ((kk_) < 2) ? xbf : cellbf; \
    const int co_ = ((kk_) & 1) * 64; \
    const size_t b0_ = (size_t)(((mg*ONT + (t_))*128) + r0)*ROWSTR + h*Aa + co_ + q0*8; \
    pa = *(const u16x8*)(as_ + b0_); \
    pb = *(const u16x8*)(as_ + b0_ + (size_t)64*ROWSTR); \
  } while(0)

  f32x4 acc[2][4];
  #pragma unroll
  for (int i = 0; i < 2; ++i)
    #pragma unroll
    for (int j = 0; j < 4; ++j) acc[i][j] = (f32x4){0.f,0.f,0.f,0.f};

  u16x8 pa0, pa1;
  OA_LOAD(pa0, pa1, 0, 0);
  *(u16x8*)((char*)lA[0] + lw0) = pa0;
  *(u16x8*)((char*)lA[0] + lw1) = pa1;
  OA_LOAD(pa0, pa1, 0, 1);
  __syncthreads();

  for (int t = 0; t < ONT; ++t){
    #pragma unroll
    for (int kk = 0; kk < 4; ++kk){
      const int cur = kk & 1;
      if (t < ONT-1 || kk < 3){
        *(u16x8*)((char*)lA[cur^1] + lw0) = pa0;
        *(u16x8*)((char*)lA[cur^1] + lw1) = pa1;
      }
      {
        const int t2 = t + (kk >= 2);
        if (t2 < ONT){
          const int kk2 = (kk + 2) & 3;
          OA_LOAD(pa0, pa1, t2, kk2);
        }
      }
      __syncthreads();
      #pragma unroll
      for (int ks = 0; ks < 2; ++ks){
        const int kel = ks*32 + lq*8;
        const int ra = wm*32 + ln15;
        bf16x8 af0 = __builtin_bit_cast(bf16x8,
          *(const u16x8*)((const char*)lA[cur] + ((ra*128 + kel*2) ^ ((ra & 7) << 4))));
        bf16x8 af1 = __builtin_bit_cast(bf16x8,
          *(const u16x8*)((const char*)lA[cur] + (((ra+16)*128 + kel*2) ^ (((ra+16) & 7) << 4))));
        const int kfull = kk*64 + kel;
        #pragma unroll
        for (int j = 0; j < 4; ++j){
          const int n = wn*64 + j*16 + ln15;
          bf16x8 bv = __builtin_bit_cast(bf16x8,
            *(const u16x8*)((const char*)lB + ((n*512 + kfull*2) ^ ((n & 7) << 4))));
          acc[0][j] = __builtin_amdgcn_mfma_f32_16x16x32_bf16(af0, bv, acc[0][j], 0, 0, 0);
          acc[1][j] = __builtin_amdgcn_mfma_f32_16x16x32_bf16(af1, bv, acc[1][j], 0, 0, 0);
        }
      }
      __syncthreads();
    }
    const int m0 = (mg*ONT + t)*128;
    #pragma unroll
    for (int mf = 0; mf < 2; ++mf){
      const int rowb = m0 + wm*32 + mf*16 + lq*4;
      #pragma unroll
      for (int j = 0; j < 4; ++j){
        const int d = wn*64 + j*16 + ln15;
        float bo = b_og[h*Dd + d];
        #pragma unroll
        for (int r = 0; r < 4; ++r){
          size_t oi = (size_t)(rowb + r)*ROWSTR + h*Dd + d;
          float cell = out[oi];
          out[oi] = sigf(acc[mf][j][r] + bo) * cell;
        }
        acc[mf][j] = (f32x4){0.f,0.f,0.f,0.f};
      }
    }
  }
  #undef OA_LOAD
}

extern "C" void kernel_launch(void* const* d_in, const int* in_sizes, int n_in,
                              void* d_out, int out_size, void* d_ws, size_t ws_size,
                              hipStream_t stream){
  const float* x       = (const float*)d_in[0];
  const float* w_hid   = (const float*)d_in[1];
  const float* b_hid   = (const float*)d_in[2];
  const float* w_og    = (const float*)d_in[3];
  const float* b_og    = (const float*)d_in[4];
  const float* ln_g    = (const float*)d_in[5];
  const float* ln_b    = (const float*)d_in[6];
  const float* init_cx = (const float*)d_in[7];
  float* out = (float*)d_out;

  char* ws = (char*)d_ws;
  unsigned short* csum = (unsigned short*)(ws);                       // 64 MiB (csum -> csln -> cellbf)
  unsigned int*   fu   = (unsigned int*)  (ws + ((size_t)64  << 20)); // 128 MiB
  unsigned short* xbf  = (unsigned short*)(ws + ((size_t)192 << 20)); // 64 MiB
  float*          tot  = (float*)         (ws + ((size_t)256 << 20)); // 1 MiB
  float*          Fc   = (float*)         (ws + ((size_t)257 << 20)); // 1 MiB
  float*          Cc   = (float*)         (ws + ((size_t)258 << 20)); // 1 MiB
  unsigned short* wht  = (unsigned short*)(ws + ((size_t)259 << 20)); // 3 MiB
  unsigned short* wot  = (unsigned short*)(ws + ((size_t)262 << 20)); // 1 MiB
  unsigned short* cellbf = csum;   // csln dead after k_gates; reuse for bf16 cell

  k_conv_whid<<<2048, 256, 0, stream>>>(w_hid, wht);
  k_conv_wog <<<1024, 256, 0, stream>>>(w_og,  wot);
  k_cumsum_a <<<Bb*Hh*NCH, Aa, 0, stream>>>(x, tot);
  k_cumsum_c <<<Bb*Hh*NCH, Aa, 0, stream>>>(x, tot, csum, xbf);
  k_stats_ln <<<ROWS, 256, 0, stream>>>(csum, ln_g, ln_b);
  k_gates    <<<dim3(8, 32), 512, 0, stream>>>(xbf, csum, wht, b_hid, fu);
  k_recur_a  <<<Bb*Hh*NCH, Dd, 0, stream>>>(fu, Fc, Cc);
  k_recur_c  <<<Bb*Hh*NCH, Dd, 0, stream>>>(fu, Fc, Cc, init_cx, out, cellbf);
  k_og       <<<dim3(16, 16), 512, 0, stream>>>(xbf, cellbf, wot, b_og, out);
}

// Round 6
// 405.681 us; speedup vs baseline: 1.6818x; 1.1166x over previous
//
#include <hip/hip_runtime.h>
#include <stdint.h>

#define Bb 8
#define Ss 2048
#define Hh 16
#define Aa 128
#define Dd 128
#define NGATE 384
#define KDIM 256
#define NCH 16
#define CLEN 128
#define ROWS (Bb*Ss)
#define ROWSTR (Hh*Aa)

typedef float f32x4 __attribute__((ext_vector_type(4)));
typedef __bf16 bf16x8 __attribute__((ext_vector_type(8)));
typedef unsigned short u16x8 __attribute__((ext_vector_type(8)));

static __device__ __forceinline__ unsigned short f2bf(float f){
  unsigned int u = __builtin_bit_cast(unsigned int, f);
  u += 0x7FFFu + ((u >> 16) & 1u);
  return (unsigned short)(u >> 16);
}
static __device__ __forceinline__ float bf2f(unsigned short s){
  unsigned int u = ((unsigned int)s) << 16;
  return __builtin_bit_cast(float, u);
}
static __device__ __forceinline__ float sigf(float x){ return 1.0f/(1.0f + __expf(-x)); }

// ---- w_hid -> [hy=h*2+nh][kh][n=192][k=128] bf16, XOR swizzled ----
__global__ void k_conv_whid(const float* __restrict__ w, unsigned short* __restrict__ wt){
  int idx = blockIdx.x*256 + threadIdx.x;
  const int total = Hh*KDIM*NGATE;
  for (; idx < total; idx += gridDim.x*256){
    int o = idx % NGATE; int k = (idx/NGATE) % KDIM; int h = idx/(NGATE*KDIM);
    int g = o >> 7, d = o & 127;
    int nh = d >> 6;
    int n = ((d & 63) >> 4)*48 + g*16 + (d & 15);   // 0..191
    int kh = k >> 7, kloc = k & 127;
    int P = (n*256 + kloc*2) ^ ((n & 7) << 4);
    wt[(size_t)(h*2 + nh)*(2*192*128) + (size_t)kh*(192*128) + (P>>1)] = f2bf(w[idx]);
  }
}
// ---- w_og -> [h][o=128][k=256] bf16 plain ----
__global__ void k_conv_wog(const float* __restrict__ w, unsigned short* __restrict__ wt){
  int idx = blockIdx.x*256 + threadIdx.x;
  const int total = Hh*KDIM*Dd;
  for (; idx < total; idx += gridDim.x*256){
    int o = idx % Dd; int k = (idx/Dd) % KDIM; int h = idx/(Dd*KDIM);
    wt[(size_t)h*(Dd*KDIM) + o*KDIM + k] = f2bf(w[idx]);
  }
}

// ---- cumsum pass A ----
__global__ void k_cumsum_a(const float* __restrict__ x, float* __restrict__ totals){
  int c = blockIdx.x;
  int k = c % NCH; int hb = c / NCH;
  int b = hb / Hh, h = hb % Hh;
  int a = threadIdx.x;
  const float* p = x + ((size_t)(b*Ss + k*CLEN)*Hh + h)*Aa + a;
  float run = 0.f;
  #pragma unroll 4
  for (int i = 0; i < CLEN; ++i) run += p[(size_t)i*ROWSTR];
  totals[(size_t)c*Aa + a] = run;
}

// ---- cumsum pass C: write bf16 csum + bf16 x ----
__global__ void k_cumsum_c(const float* __restrict__ x, const float* __restrict__ totals,
                           unsigned short* __restrict__ csum, unsigned short* __restrict__ xbf){
  int c = blockIdx.x;
  int k = c % NCH; int hb = c / NCH;
  int b = hb / Hh, h = hb % Hh;
  int a = threadIdx.x;
  const float* tp = totals + (size_t)hb*NCH*Aa + a;
  float run = 0.f;
  for (int j = 0; j < k; ++j) run += tp[(size_t)j*Aa];
  const size_t base = ((size_t)(b*Ss + k*CLEN)*Hh + h)*Aa + a;
  const float* p = x + base;
  unsigned short* q  = csum + base;
  unsigned short* xq = xbf  + base;
  #pragma unroll 2
  for (int i = 0; i < CLEN; ++i){
    float v = p[(size_t)i*ROWSTR];
    run += v;
    q [(size_t)i*ROWSTR] = f2bf(run);
    xq[(size_t)i*ROWSTR] = f2bf(v);
  }
}

// ---- LN stats per (b,s) row -> (mean, rstd) ----
__global__ void k_stats(const unsigned short* __restrict__ csum, float2* __restrict__ mr){
  int r = blockIdx.x;
  int t = threadIdx.x;
  const u16x8 v = *(const u16x8*)(csum + (size_t)r*ROWSTR + t*8);
  float s = 0.f, q = 0.f;
  #pragma unroll
  for (int i = 0; i < 8; ++i){ float f = bf2f(v[i]); s += f; q += f*f; }
  #pragma unroll
  for (int off = 32; off; off >>= 1){ s += __shfl_down(s, off); q += __shfl_down(q, off); }
  __shared__ float ls[4], lq[4];
  int wid = t >> 6, lane = t & 63;
  if (lane == 0){ ls[wid] = s; lq[wid] = q; }
  __syncthreads();
  if (t == 0){
    float S2 = ls[0]+ls[1]+ls[2]+ls[3], Q = lq[0]+lq[1]+lq[2]+lq[3];
    float mu = S2 * (1.0f/(float)ROWSTR);
    float var = Q * (1.0f/(float)ROWSTR) - mu*mu;
    mr[r] = make_float2(mu, rsqrtf(var + 1e-6f));
  }
}

// ---- gates GEMM v4: 2 blocks/CU, B per-K-half, LN fused, 2m x 4n waves ----
#define GSRC(kk_) (((kk_) < 2) ? xbf : csum)
#define GCO(kk_)  (((kk_) & 1) * 64)
#define GROW(p_)  ((mg*8 + ((p_) >> 2))*128)
__launch_bounds__(512, 4)
__global__ void k_gates(const unsigned short* __restrict__ xbf,
                        const unsigned short* __restrict__ csum,
                        const float2* __restrict__ mr,
                        const float* __restrict__ ln_g, const float* __restrict__ ln_b,
                        const unsigned short* __restrict__ wht,
                        const float* __restrict__ b_hid, unsigned int* __restrict__ fu){
  __shared__ unsigned short lB[192*128];       // 48 KiB
  __shared__ unsigned short lA[2][128*64];     // 32 KiB
  const int mg = blockIdx.x, hy = blockIdx.y;
  const int h = hy >> 1, nh = hy & 1;
  const int tid = threadIdx.x;
  const int lane = tid & 63, wid = tid >> 6;
  const int wm = wid & 1, wn = wid >> 1;       // 2m(64 rows) x 4n(48 cols)
  const int ln15 = lane & 15, lq = lane >> 4;
  const int r0 = tid >> 3, q0 = tid & 7;
  const int lwA0 = (r0*128 + q0*16) ^ ((r0 & 7) << 4);
  const int lwA1 = ((r0+64)*128 + q0*16) ^ ((r0 & 7) << 4);
  const unsigned short* bsrc = wht + (size_t)hy*(2*192*128);

  f32x4 acc[4][3];
  #pragma unroll
  for (int i = 0; i < 4; ++i)
    #pragma unroll
    for (int j = 0; j < 3; ++j) acc[i][j] = (f32x4){0.f,0.f,0.f,0.f};

  u16x8 pa0, pa1, pb0, pb1, pb2, pb3, pb4, pb5;

#define GA_FETCH(p_) do { \
    const unsigned short* as_ = GSRC((p_) & 3); \
    const size_t base_ = (size_t)(GROW(p_) + r0)*ROWSTR + h*Aa + GCO((p_) & 3) + q0*8; \
    pa0 = *(const u16x8*)(as_ + base_); \
    pa1 = *(const u16x8*)(as_ + base_ + (size_t)64*ROWSTR); \
  } while(0)
#define GB_FETCH(p_) do { \
    const u16x8* bs_ = (const u16x8*)(bsrc + (size_t)((((p_) >> 1) & 1))*(192*128)); \
    pb0 = bs_[tid]; pb1 = bs_[tid+512]; pb2 = bs_[tid+1024]; \
    pb3 = bs_[tid+1536]; pb4 = bs_[tid+2048]; pb5 = bs_[tid+2560]; \
  } while(0)
#define GA_WRITE(p_, buf_) do { \
    const int kkw_ = (p_) & 3; \
    if (kkw_ >= 2){ \
      float2 m0_ = mr[GROW(p_) + r0]; \
      float2 m1_ = mr[GROW(p_) + r0 + 64]; \
      const float* g_ = ln_g + h*Aa + GCO(kkw_) + q0*8; \
      const float* bz_ = ln_b + h*Aa + GCO(kkw_) + q0*8; \
      u16x8 o0_, o1_; \
      _Pragma("unroll") \
      for (int i_ = 0; i_ < 8; ++i_){ \
        float gg_ = g_[i_], bb_ = bz_[i_]; \
        o0_[i_] = f2bf((bf2f(pa0[i_]) - m0_.x)*m0_.y*gg_ + bb_); \
        o1_[i_] = f2bf((bf2f(pa1[i_]) - m1_.x)*m1_.y*gg_ + bb_); \
      } \
      *(u16x8*)((char*)lA[buf_] + lwA0) = o0_; \
      *(u16x8*)((char*)lA[buf_] + lwA1) = o1_; \
    } else { \
      *(u16x8*)((char*)lA[buf_] + lwA0) = pa0; \
      *(u16x8*)((char*)lA[buf_] + lwA1) = pa1; \
    } \
  } while(0)

  // prologue
  GA_FETCH(0); GA_WRITE(0, 0);
  GA_FETCH(1);
  GB_FETCH(0);

  for (int p = 0; p < 32; ++p){
    const int cur = p & 1;
    if (!(p & 1)){
      u16x8* lb8 = (u16x8*)lB;
      lb8[tid] = pb0; lb8[tid+512] = pb1; lb8[tid+1024] = pb2;
      lb8[tid+1536] = pb3; lb8[tid+2048] = pb4; lb8[tid+2560] = pb5;
      if (p + 2 < 32) GB_FETCH(p+2);
    }
    if (p + 1 < 32) GA_WRITE(p+1, cur^1);
    if (p + 2 < 32) GA_FETCH(p+2);
    __syncthreads();
    #pragma unroll
    for (int ks = 0; ks < 2; ++ks){
      const int kel = ks*32 + lq*8;
      bf16x8 af[4];
      #pragma unroll
      for (int mf = 0; mf < 4; ++mf){
        int ra = wm*64 + mf*16 + ln15;
        af[mf] = __builtin_bit_cast(bf16x8,
          *(const u16x8*)((const char*)lA[cur] + ((ra*128 + kel*2) ^ ((ra & 7) << 4))));
      }
      const int kloc = (p & 1)*64 + kel;
      #pragma unroll
      for (int g = 0; g < 3; ++g){
        int n = wn*48 + g*16 + ln15;
        bf16x8 bv = __builtin_bit_cast(bf16x8,
          *(const u16x8*)((const char*)lB + ((n*256 + kloc*2) ^ ((n & 7) << 4))));
        #pragma unroll
        for (int mf = 0; mf < 4; ++mf)
          acc[mf][g] = __builtin_amdgcn_mfma_f32_16x16x32_bf16(af[mf], bv, acc[mf][g], 0, 0, 0);
      }
    }
    __syncthreads();
    if ((p & 3) == 3){
      const int m0 = GROW(p);
      const int d = nh*64 + wn*16 + ln15;
      const float big = b_hid[h*NGATE + d];
      const float bfg = b_hid[h*NGATE + 128 + d];
      const float bhd = b_hid[h*NGATE + 256 + d];
      #pragma unroll
      for (int mf = 0; mf < 4; ++mf){
        const int rowb = m0 + wm*64 + mf*16 + lq*4;
        f32x4 aig = acc[mf][0], afg = acc[mf][1], ahd = acc[mf][2];
        #pragma unroll
        for (int r = 0; r < 4; ++r){
          float fg = sigf(afg[r] + bfg);
          float uu = sigf(aig[r] + big) * fmaxf(ahd[r] + bhd, 0.0f);
          fu[(size_t)(rowb + r)*ROWSTR + h*Dd + d] =
            ((unsigned int)f2bf(uu) << 16) | (unsigned int)f2bf(fg);
        }
        acc[mf][0] = (f32x4){0.f,0.f,0.f,0.f};
        acc[mf][1] = (f32x4){0.f,0.f,0.f,0.f};
        acc[mf][2] = (f32x4){0.f,0.f,0.f,0.f};
      }
    }
  }
#undef GA_FETCH
#undef GB_FETCH
#undef GA_WRITE
}

// ---- recurrence pass A: per-128-chunk (F, C) ----
__global__ void k_recur_a(const unsigned int* __restrict__ fu,
                          float* __restrict__ Fc, float* __restrict__ Cc){
  int c = blockIdx.x;
  int k = c % NCH; int hb = c / NCH;
  int b = hb / Hh, h = hb % Hh;
  int d = threadIdx.x;
  const unsigned int* p = fu + ((size_t)(b*Ss + k*CLEN)*Hh + h)*Dd + d;
  float F = 1.f, C = 0.f;
  #pragma unroll 4
  for (int i = 0; i < CLEN; ++i){
    unsigned int v = p[(size_t)i*ROWSTR];
    float f = bf2f((unsigned short)v);
    float u = bf2f((unsigned short)(v >> 16));
    C = fmaf(f, C, u);
    F *= f;
  }
  Fc[(size_t)c*Dd + d] = F;
  Cc[(size_t)c*Dd + d] = C;
}

// ---- recurrence pass B: carry BEFORE each chunk ----
__global__ void k_recur_b(const float* __restrict__ Fc, const float* __restrict__ Cc,
                          const float* __restrict__ init_cx, float* __restrict__ gcarry){
  int bh = blockIdx.x;          // b*Hh + h
  int h = bh % Hh;
  int d = threadIdx.x;
  float carry = init_cx[h*Dd + d];
  for (int j = 0; j < NCH; ++j){
    size_t o = ((size_t)bh*NCH + j)*Dd + d;
    gcarry[o] = carry;
    carry = fmaf(Fc[o], carry, Cc[o]);
  }
}

// ---- fused recurrence + og GEMM + gating ----
#define CPITCH 132
#define XPITCH 136
__launch_bounds__(512, 2)
__global__ void k_og_fused(const unsigned short* __restrict__ xbf,
                           const unsigned int* __restrict__ fu,
                           const unsigned short* __restrict__ wot,
                           const float* __restrict__ gcarry,
                           const float* __restrict__ b_og, float* __restrict__ out){
  __shared__ float s_cell[128*CPITCH];          // 67584 B (fp32 cell; B-stage reuses)
  __shared__ unsigned short s_xa[128*XPITCH];   // 34816 B (x half, bf16, padded)
  __shared__ float2 s_scan[4*128];              // 4 KiB
  __shared__ float s_cc[128];
  const int mg = blockIdx.x;    // 16
  const int h  = blockIdx.y;    // 16
  const int tid = threadIdx.x;
  const int lane = tid & 63, wid = tid >> 6;
  const int wm = wid >> 2, wn = wid & 3;        // 2m(64 rows) x 4n(32 cols)
  const int ln15 = lane & 15, lq = lane >> 4;
  const int rd = tid & 127, rq = tid >> 7;      // recurrence: d, quarter

  // B (w_og for this head) -> regs via LDS stage
  bf16x8 Bf[8][2];
  {
    unsigned short* bst = (unsigned short*)s_cell;
    const u16x8* bs = (const u16x8*)(wot + (size_t)h*(Dd*KDIM));
    u16x8* d8 = (u16x8*)bst;
    #pragma unroll
    for (int i = 0; i < 8; ++i) d8[tid + i*512] = bs[tid + i*512];
    if (tid < 128)
      s_cc[tid] = gcarry[((size_t)((mg>>1)*Hh + h)*NCH + (mg & 1)*8)*Dd + tid];
    __syncthreads();
    #pragma unroll
    for (int ks = 0; ks < 8; ++ks)
      #pragma unroll
      for (int j = 0; j < 2; ++j){
        int n = wn*32 + j*16 + ln15;
        Bf[ks][j] = __builtin_bit_cast(bf16x8,
          *(const u16x8*)(bst + n*KDIM + ks*32 + lq*8));
      }
    __syncthreads();
  }

  f32x4 acc[4][2];
  #pragma unroll
  for (int i = 0; i < 4; ++i){ acc[i][0] = (f32x4){0,0,0,0}; acc[i][1] = (f32x4){0,0,0,0}; }

  for (int t = 0; t < 8; ++t){
    const int row0 = (mg*8 + t)*128;
    // fu chunk -> regs
    unsigned int uf[32];
    const unsigned int* fp = fu + (size_t)(row0 + rq*32)*ROWSTR + h*Dd + rd;
    #pragma unroll
    for (int i = 0; i < 32; ++i) uf[i] = fp[(size_t)i*ROWSTR];
    // stage x half
    #pragma unroll
    for (int i = 0; i < 4; ++i){
      int c = tid + i*512;
      int r = c >> 4, c8 = c & 15;
      u16x8 v = *(const u16x8*)(xbf + (size_t)(row0 + r)*ROWSTR + h*Aa + c8*8);
      *(u16x8*)&s_xa[r*XPITCH + c8*8] = v;
    }
    // local (F,C) over 32 rows
    float F = 1.f, C = 0.f;
    #pragma unroll
    for (int i = 0; i < 32; ++i){
      float f = bf2f((unsigned short)uf[i]);
      float u = bf2f((unsigned short)(uf[i] >> 16));
      C = fmaf(f, C, u); F *= f;
    }
    s_scan[rq*128 + rd] = make_float2(F, C);
    __syncthreads();
    // carry-in per quarter
    float cin = s_cc[rd];
    #pragma unroll
    for (int qq = 0; qq < 3; ++qq){
      if (rq > qq){ float2 s = s_scan[qq*128 + rd]; cin = fmaf(s.x, cin, s.y); }
    }
    __syncthreads();    // all cc reads done
    if (rq == 3){ float2 s3 = s_scan[3*128 + rd]; s_cc[rd] = fmaf(s3.x, cin, s3.y); }
    // replay -> cell fp32 in LDS
    {
      float c = cin;
      #pragma unroll
      for (int i = 0; i < 32; ++i){
        float f = bf2f((unsigned short)uf[i]);
        float u = bf2f((unsigned short)(uf[i] >> 16));
        c = fmaf(f, c, u);
        s_cell[(rq*32 + i)*CPITCH + rd] = c;
      }
    }
    __syncthreads();
    // GEMM: phase 1 (x half, bf16)
    #pragma unroll
    for (int ks = 0; ks < 4; ++ks){
      bf16x8 af[4];
      #pragma unroll
      for (int mf = 0; mf < 4; ++mf){
        int ra = wm*64 + mf*16 + ln15;
        af[mf] = __builtin_bit_cast(bf16x8,
          *(const u16x8*)&s_xa[ra*XPITCH + ks*32 + lq*8]);
      }
      #pragma unroll
      for (int mf = 0; mf < 4; ++mf)
        #pragma unroll
        for (int j = 0; j < 2; ++j)
          acc[mf][j] = __builtin_amdgcn_mfma_f32_16x16x32_bf16(af[mf], Bf[ks][j], acc[mf][j], 0, 0, 0);
    }
    // GEMM: phase 2 (cell half, fp32 -> bf16 on read)
    #pragma unroll
    for (int ks = 4; ks < 8; ++ks){
      bf16x8 af[4];
      #pragma unroll
      for (int mf = 0; mf < 4; ++mf){
        int ra = wm*64 + mf*16 + ln15;
        const float* cp = &s_cell[ra*CPITCH + (ks-4)*32 + lq*8];
        f32x4 c0 = *(const f32x4*)cp;
        f32x4 c1 = *(const f32x4*)(cp + 4);
        u16x8 tt;
        tt[0]=f2bf(c0[0]); tt[1]=f2bf(c0[1]); tt[2]=f2bf(c0[2]); tt[3]=f2bf(c0[3]);
        tt[4]=f2bf(c1[0]); tt[5]=f2bf(c1[1]); tt[6]=f2bf(c1[2]); tt[7]=f2bf(c1[3]);
        af[mf] = __builtin_bit_cast(bf16x8, tt);
      }
      #pragma unroll
      for (int mf = 0; mf < 4; ++mf)
        #pragma unroll
        for (int j = 0; j < 2; ++j)
          acc[mf][j] = __builtin_amdgcn_mfma_f32_16x16x32_bf16(af[mf], Bf[ks][j], acc[mf][j], 0, 0, 0);
    }
    // epilogue: out = sigmoid(acc + b) * cell(fp32)
    #pragma unroll
    for (int mf = 0; mf < 4; ++mf){
      const int rl = wm*64 + mf*16 + lq*4;
      #pragma unroll
      for (int j = 0; j < 2; ++j){
        const int d = wn*32 + j*16 + ln15;
        const float bo = b_og[h*Dd + d];
        #pragma unroll
        for (int r = 0; r < 4; ++r){
          float cell = s_cell[(rl + r)*CPITCH + d];
          out[(size_t)(row0 + rl + r)*ROWSTR + h*Dd + d] = sigf(acc[mf][j][r] + bo) * cell;
        }
        acc[mf][j] = (f32x4){0.f,0.f,0.f,0.f};
      }
    }
    __syncthreads();   // protect cell/xa before next tile
  }
}

extern "C" void kernel_launch(void* const* d_in, const int* in_sizes, int n_in,
                              void* d_out, int out_size, void* d_ws, size_t ws_size,
                              hipStream_t stream){
  const float* x       = (const float*)d_in[0];
  const float* w_hid   = (const float*)d_in[1];
  const float* b_hid   = (const float*)d_in[2];
  const float* w_og    = (const float*)d_in[3];
  const float* b_og    = (const float*)d_in[4];
  const float* ln_g    = (const float*)d_in[5];
  const float* ln_b    = (const float*)d_in[6];
  const float* init_cx = (const float*)d_in[7];
  float* out = (float*)d_out;

  char* ws = (char*)d_ws;
  unsigned short* csum = (unsigned short*)(ws);                       // 64 MiB
  unsigned int*   fu   = (unsigned int*)  (ws + ((size_t)64  << 20)); // 128 MiB
  unsigned short* xbf  = (unsigned short*)(ws + ((size_t)192 << 20)); // 64 MiB
  float*          tot  = (float*)         (ws + ((size_t)256 << 20)); // 1 MiB
  float*          Fc   = (float*)         (ws + ((size_t)257 << 20)); // 1 MiB
  float*          Cc   = (float*)         (ws + ((size_t)258 << 20)); // 1 MiB
  float2*         mr   = (float2*)        (ws + ((size_t)259 << 20)); // 128 KiB
  unsigned short* wht  = (unsigned short*)(ws + ((size_t)260 << 20)); // 3 MiB
  unsigned short* wot  = (unsigned short*)(ws + ((size_t)263 << 20)); // 1 MiB
  float*          gcar = (float*)         (ws + ((size_t)264 << 20)); // 1 MiB

  k_conv_whid<<<2048, 256, 0, stream>>>(w_hid, wht);
  k_conv_wog <<<1024, 256, 0, stream>>>(w_og,  wot);
  k_cumsum_a <<<Bb*Hh*NCH, Aa, 0, stream>>>(x, tot);
  k_cumsum_c <<<Bb*Hh*NCH, Aa, 0, stream>>>(x, tot, csum, xbf);
  k_stats    <<<ROWS, 256, 0, stream>>>(csum, mr);
  k_gates    <<<dim3(16, 32), 512, 0, stream>>>(xbf, csum, mr, ln_g, ln_b, wht, b_hid, fu);
  k_recur_a  <<<Bb*Hh*NCH, Dd, 0, stream>>>(fu, Fc, Cc);
  k_recur_b  <<<Bb*Hh, Dd, 0, stream>>>(Fc, Cc, init_cx, gcar);
  k_og_fused <<<dim3(16, 16), 512, 0, stream>>>(xbf, fu, wot, gcar, b_og, out);
}